// Round 4
// baseline (184.321 us; speedup 1.0000x reference)
//
#include <hip/hip_runtime.h>
#include <cstdint>
#include <cstddef>

// ---------------------------------------------------------------------------
// HierarchicalQueryMatcher, N=2048, W=64, D=512.
//   LN1(x)@w1+b1 = rs*(A[n,:]+B[w,:]) - rs*mu*G + C
//   h2 = gelu(h) @ w2 ; y = h2 + q[n] + b2
//   out = 16 * dot(LN2(y), cmhat)/max(||LN2(y)||,eps)
// Linear-in-h2 sums folded into extra GEMM cols (M6 = w2@cmhg^T, v1,v3,v4);
// quadratic sums (S2, S5) streamed in the MFMA epilogue.
// k_main round 4: M=64 pairs/wave (2n x 2wtile af sets, 256 regs) to halve
// per-CU LDS w2-fragment traffic (the measured bottleneck).
// ---------------------------------------------------------------------------

#define NQ 2048
#define NWC 64
#define DD 512
#define NCHUNK 19

typedef __attribute__((ext_vector_type(8))) short short8;
typedef __attribute__((ext_vector_type(8))) unsigned short ushort8;
typedef __attribute__((ext_vector_type(4))) float f32x4;

__device__ __forceinline__ unsigned short f2bf(float f) {
  unsigned u = __float_as_uint(f);
  u += 0x7fffu + ((u >> 16) & 1u);
  return (unsigned short)(u >> 16);
}

__device__ __forceinline__ unsigned cvtpk2(float lo, float hi) {
  unsigned r;
  asm("v_cvt_pk_bf16_f32 %0, %1, %2" : "=v"(r) : "v"(lo), "v"(hi));
  return r;
}

__device__ __forceinline__ float bf2f(unsigned short u) {
  return __uint_as_float(((unsigned)u) << 16);
}

__device__ __forceinline__ float gelu_f(float h) {
  float h2 = h * h;
  float z2 = h * fmaf(h2, 0.10295890518f, 2.30221607f); // *log2(e)
  float e = exp2f(z2);
  return h * (e * __builtin_amdgcn_rcpf(e + 1.0f));
}

__device__ __forceinline__ float wred(float v) {
#pragma unroll
  for (int m = 1; m < 64; m <<= 1) v += __shfl_xor(v, m, 64);
  return v;
}

__device__ __forceinline__ float sel4(f32x4 v, int r) {
  float x = (r & 1) ? v[1] : v[0];
  float y = (r & 1) ? v[3] : v[2];
  return (r & 2) ? y : x;
}

// ---------------- k_prep: all O(N*D) precompute in one launch ----------------
__global__ __launch_bounds__(256) void k_prep(
    const float* __restrict__ q, const float* __restrict__ cm,
    const float* __restrict__ g1, const float* __restrict__ be1,
    const float* __restrict__ w1, const float* __restrict__ w2,
    const float* __restrict__ g2, const float* __restrict__ be2,
    const float* __restrict__ b2,
    float* __restrict__ Sq, float* __restrict__ SSq, float* __restrict__ qst,
    float* __restrict__ Sc, float* __restrict__ SSc, float* __restrict__ cmhg,
    float* __restrict__ c1, float* __restrict__ c2, float* __restrict__ c3,
    float* __restrict__ Gp, float* __restrict__ Cp, float* __restrict__ V,
    float* __restrict__ gg, float* __restrict__ scal) {
  const int b = blockIdx.x, tid = threadIdx.x;
  const int wv = tid >> 6, l = tid & 63;
  __shared__ float shr[3][4];
  __shared__ float s_inv;

  if (b < 256) {
    f32x4 b20 = *(const f32x4*)(b2 + l * 8);
    f32x4 b21 = *(const f32x4*)(b2 + l * 8 + 4);
    f32x4 g20 = *(const f32x4*)(g2 + l * 8);
    f32x4 g21 = *(const f32x4*)(g2 + l * 8 + 4);
    f32x4 e20 = *(const f32x4*)(be2 + l * 8);
    f32x4 e21 = *(const f32x4*)(be2 + l * 8 + 4);
#pragma unroll
    for (int rr = 0; rr < 2; ++rr) {
      int r = b * 8 + wv * 2 + rr;
      const float* row = q + (size_t)r * DD;
      f32x4 q0 = *(const f32x4*)(row + l * 8);
      f32x4 q1 = *(const f32x4*)(row + l * 8 + 4);
      float s0 = 0, s1 = 0, s2 = 0, s3 = 0, s4 = 0;
#pragma unroll
      for (int i = 0; i < 4; ++i) {
        float v = q0[i]; s0 += v; s1 = fmaf(v, v, s1);
        float qb = v + b20[i], g = g20[i];
        s2 += qb; s3 = fmaf(qb, g * g, s3); s4 = fmaf(qb, g * e20[i], s4);
        v = q1[i]; s0 += v; s1 = fmaf(v, v, s1);
        qb = v + b21[i]; g = g21[i];
        s2 += qb; s3 = fmaf(qb, g * g, s3); s4 = fmaf(qb, g * e21[i], s4);
      }
      s0 = wred(s0); s1 = wred(s1); s2 = wred(s2); s3 = wred(s3); s4 = wred(s4);
      if (l == 0) {
        Sq[r] = s0; SSq[r] = s1;
        qst[r * 4 + 0] = s2; qst[r * 4 + 1] = s3; qst[r * 4 + 2] = s4;
      }
    }
  } else if (b < 320) {
    int w = b - 256;
    const float* row = cm + (size_t)w * DD;
    float sm = 0.f, ss = 0.f;
    for (int c = tid; c < DD; c += 256) { float v = row[c]; sm += v; ss = fmaf(v, v, ss); }
    sm = wred(sm); ss = wred(ss);
    if (l == 0) { shr[0][wv] = sm; shr[1][wv] = ss; }
    __syncthreads();
    if (tid == 0) {
      float smt = shr[0][0] + shr[0][1] + shr[0][2] + shr[0][3];
      float sst = shr[1][0] + shr[1][1] + shr[1][2] + shr[1][3];
      Sc[w] = smt; SSc[w] = sst;
      s_inv = 1.0f / fmaxf(sqrtf(sst), 1e-12f);
    }
    __syncthreads();
    float inv = s_inv;
    float a = 0.f, bs = 0.f, d = 0.f;
    for (int c = tid; c < DD; c += 256) {
      float ch = row[c] * inv;
      float gv = g2[c];
      float gch = gv * ch;
      cmhg[(size_t)w * DD + c] = gch;
      a += gch;
      bs = fmaf(be2[c], ch, bs);
      d = fmaf(b2[c], gch, d);
    }
    a = wred(a); bs = wred(bs); d = wred(d);
    __syncthreads();
    if (l == 0) { shr[0][wv] = a; shr[1][wv] = bs; shr[2][wv] = d; }
    __syncthreads();
    if (tid == 0) {
      c1[w] = shr[0][0] + shr[0][1] + shr[0][2] + shr[0][3];
      c2[w] = shr[1][0] + shr[1][1] + shr[1][2] + shr[1][3];
      c3[w] = shr[2][0] + shr[2][1] + shr[2][2] + shr[2][3];
    }
  } else if (b < 336) {
    int bk = b - 320, k0 = bk * 64;
#pragma unroll
    for (int jh = 0; jh < 2; ++jh) {
      int j = tid + jh * 256;
      float g = 0.f, c = 0.f;
#pragma unroll 4
      for (int k = 0; k < 64; ++k) {
        float wv4 = w1[(size_t)(k0 + k) * DD + j];
        g = fmaf(g1[k0 + k], wv4, g);
        c = fmaf(be1[k0 + k], wv4, c);
      }
      Gp[(size_t)bk * DD + j] = g;
      Cp[(size_t)bk * DD + j] = c;
    }
  } else if (b < 400) {
    int bb = b - 336;
    f32x4 g20 = *(const f32x4*)(g2 + l * 8);
    f32x4 g21 = *(const f32x4*)(g2 + l * 8 + 4);
    f32x4 e20 = *(const f32x4*)(be2 + l * 8);
    f32x4 e21 = *(const f32x4*)(be2 + l * 8 + 4);
#pragma unroll
    for (int rr = 0; rr < 2; ++rr) {
      int k = bb * 8 + wv * 2 + rr;
      const float* row = w2 + (size_t)k * DD;
      f32x4 w0 = *(const f32x4*)(row + l * 8);
      f32x4 w1v = *(const f32x4*)(row + l * 8 + 4);
      float s1 = 0, s3 = 0, s4 = 0;
#pragma unroll
      for (int i = 0; i < 4; ++i) {
        float w = w0[i], g = g20[i];
        s1 += w; s3 = fmaf(w, g * g, s3); s4 = fmaf(w, g * e20[i], s4);
        w = w1v[i]; g = g21[i];
        s1 += w; s3 = fmaf(w, g * g, s3); s4 = fmaf(w, g * e21[i], s4);
      }
      s1 = wred(s1); s3 = wred(s3); s4 = wred(s4);
      if (l == 0) {
        V[k * 4 + 0] = s1; V[k * 4 + 1] = s3; V[k * 4 + 2] = s4; V[k * 4 + 3] = 0.f;
      }
    }
  } else {
    float a0 = 0, a1 = 0, a2 = 0;
    for (int c = tid; c < DD; c += 256) {
      float g = g2[c], be = be2[c];
      gg[c] = g * g;
      a0 = fmaf(g, g, a0); a1 = fmaf(g, be, a1); a2 = fmaf(be, be, a2);
    }
    a0 = wred(a0); a1 = wred(a1); a2 = wred(a2);
    if (l == 0) { shr[0][wv] = a0; shr[1][wv] = a1; shr[2][wv] = a2; }
    __syncthreads();
    if (tid == 0) {
      scal[0] = shr[0][0] + shr[0][1] + shr[0][2] + shr[0][3];
      scal[1] = shr[1][0] + shr[1][1] + shr[1][2] + shr[1][3];
      scal[2] = shr[2][0] + shr[2][1] + shr[2][2] + shr[2][3];
    }
  }
}

// ---------------- k_pack1: PW1T + PW1B + PCT ----------------
__global__ __launch_bounds__(512) void k_pack1(
    const float* __restrict__ w1, const float* __restrict__ ln1w,
    const float* __restrict__ cmhg,
    unsigned short* __restrict__ PW1T, unsigned short* __restrict__ PW1B,
    unsigned short* __restrict__ PCT) {
  int b = blockIdx.x;
  if (b < 128) {
    int roff = (b < 64) ? 0 : 512;
    unsigned short* out = (b < 64) ? PW1T : PW1B;
    int tid = (b & 63) * 512 + threadIdx.x;
    int l = tid & 63, t = (tid >> 6) & 15, ct = tid >> 10, g = l >> 4;
    int col = (ct << 4) + (l & 15);
    ushort8 o;
#pragma unroll
    for (int i = 0; i < 8; ++i) {
      int k = t * 32 + g * 8 + i;
      o[i] = f2bf(w1[(size_t)(roff + k) * DD + col] * ln1w[roff + k]);
    }
    *(ushort8*)(out + (size_t)tid * 8) = o;
  } else {
    int tid = (b - 128) * 512 + threadIdx.x;
    int l = tid & 63, t = (tid >> 6) & 15, g = l >> 4;
    int col = ((tid >> 10) << 4) + (l & 15);
    ushort8 o;
#pragma unroll
    for (int i = 0; i < 8; ++i) {
      int k = t * 32 + g * 8 + i;
      o[i] = f2bf(cmhg[(size_t)col * DD + k]);
    }
    *(ushort8*)(PCT + (size_t)tid * 8) = o;
  }
}

// ---------------- k_gemms: 4 GEMM jobs in one dispatch ----------------
__global__ __launch_bounds__(256) void k_gemms(
    const float* __restrict__ q, const float* __restrict__ cm,
    const float* __restrict__ w2,
    const unsigned short* __restrict__ PW1T, const unsigned short* __restrict__ PW1B,
    const unsigned short* __restrict__ PCT,
    float* __restrict__ A, unsigned short* __restrict__ Bwb,
    float* __restrict__ QC, float* __restrict__ M6) {
  int b = blockIdx.x;
  const float* X; const unsigned short* PW; void* Out;
  int bx, by, ostride, obf;
  if (b < 256)      { X = q;  PW = PW1T; Out = A;    bx = b & 7;   by = b >> 3;  ostride = DD;  obf = 0; }
  else if (b < 264) { X = cm; PW = PW1B; Out = Bwb;  bx = b - 256; by = 0;       ostride = DD;  obf = 1; }
  else if (b < 296) { X = q;  PW = PCT;  Out = QC;   bx = 0;       by = b - 264; ostride = NWC; obf = 0; }
  else              { X = w2; PW = PCT;  Out = M6;   bx = 0;       by = b - 296; ostride = NWC; obf = 0; }

  int l = threadIdx.x & 63;
  int wv = threadIdx.x >> 6;
  int lr = l & 15, g = l >> 4;
  int r0 = by * 64 + wv * 16;
  int cb0 = bx * 4;
  f32x4 acc[4] = {{0,0,0,0},{0,0,0,0},{0,0,0,0},{0,0,0,0}};
  const float* xrow = X + (size_t)(r0 + lr) * DD;
#pragma unroll
  for (int t = 0; t < 16; ++t) {
    int kb = t * 32 + g * 8;
    f32x4 x0 = *(const f32x4*)(xrow + kb);
    f32x4 x1 = *(const f32x4*)(xrow + kb + 4);
    union { short8 s; unsigned u[4]; } af;
    af.u[0] = cvtpk2(x0[0], x0[1]);
    af.u[1] = cvtpk2(x0[2], x0[3]);
    af.u[2] = cvtpk2(x1[0], x1[1]);
    af.u[3] = cvtpk2(x1[2], x1[3]);
#pragma unroll
    for (int c = 0; c < 4; ++c) {
      short8 bf = *(const short8*)(PW + (size_t)(((cb0 + c) * 16 + t) * 64 + l) * 8);
      acc[c] = __builtin_amdgcn_mfma_f32_16x16x32_bf16(af.s, bf, acc[c], 0, 0, 0);
    }
  }
#pragma unroll
  for (int c = 0; c < 4; ++c)
#pragma unroll
    for (int r = 0; r < 4; ++r) {
      size_t idx = (size_t)(r0 + g * 4 + r) * ostride + (cb0 + c) * 16 + lr;
      float v = acc[c][r];
      if (obf) ((unsigned short*)Out)[idx] = f2bf(v);
      else     ((float*)Out)[idx] = v;
    }
}

// ---------------- k_pack2: PW2X + PBw + G/C reduce ----------------
__global__ __launch_bounds__(512) void k_pack2(
    const float* __restrict__ w2, const float* __restrict__ M6,
    const float* __restrict__ V, const unsigned short* __restrict__ Bwb,
    const float* __restrict__ Gp, const float* __restrict__ Cp,
    const float* __restrict__ b1,
    unsigned short* __restrict__ PW2X, unsigned short* __restrict__ PBw,
    float* __restrict__ G, float* __restrict__ C) {
  int b = blockIdx.x;
  if (b < 76) {
    int tid = b * 512 + threadIdx.x;
    int l = tid & 63, t = (tid >> 6) & 15, ct = tid >> 10, g = l >> 4;
    int col = (ct << 4) + (l & 15);
    ushort8 o;
#pragma unroll
    for (int i = 0; i < 8; ++i) {
      int k = t * 32 + g * 8 + i;
      float v;
      if (col < 512)      v = w2[(size_t)k * DD + col];
      else if (col < 576) v = M6[(size_t)k * 64 + (col - 512)];
      else { int cv = col - 576; v = (cv < 3) ? V[k * 4 + cv] : 0.f; }
      o[i] = f2bf(v);
    }
    *(ushort8*)(PW2X + (size_t)tid * 8) = o;
  } else if (b < 84) {
    int tid = (b - 76) * 512 + threadIdx.x;
    int l = tid & 63, t = (tid >> 6) & 15, wt = tid >> 10;
    ushort8 o;
#pragma unroll
    for (int i = 0; i < 8; ++i)
      o[i] = Bwb[(size_t)(wt * 16 + (l & 15)) * DD + t * 32 + (l >> 4) * 8 + i];
    *(ushort8*)(PBw + (size_t)tid * 8) = o;
  } else {
    int c = threadIdx.x;
    float g = 0.f, cc = 0.f;
#pragma unroll
    for (int p = 0; p < 16; ++p) { g += Gp[p * DD + c]; cc += Cp[p * DD + c]; }
    G[c] = g; C[c] = cc + b1[c];
  }
}

// ---------------- fused main kernel: M=64 pairs/wave --------------

__device__ __forceinline__ void async16(const void* g, void* lds) {
  __builtin_amdgcn_global_load_lds(
      (const __attribute__((address_space(1))) void*)(uintptr_t)g,
      (__attribute__((address_space(3))) void*)(unsigned int)(uintptr_t)lds,
      16, 0, 0);
}

__global__ __launch_bounds__(256, 1) void k_main(
    const float* __restrict__ Afull, const unsigned short* __restrict__ PBw,
    const float* __restrict__ G, const float* __restrict__ Cc,
    const float* __restrict__ q, const float* __restrict__ b2,
    const float* __restrict__ gg, const float* __restrict__ qst,
    const float* __restrict__ QC, const float* __restrict__ c1v,
    const float* __restrict__ c2v, const float* __restrict__ c3v,
    const float* __restrict__ Sq, const float* __restrict__ SSq,
    const float* __restrict__ Sc, const float* __restrict__ SSc,
    const float* __restrict__ scal, const unsigned short* __restrict__ PW2X,
    float* __restrict__ out) {

  __shared__ __align__(16) float sG[DD], sC[DD], sGG[DD];
  __shared__ __align__(16) float sA[4][DD], sQB[4][DD];
  __shared__ __align__(16) unsigned short sW[2][16384];   // 32KB chunk dbuf

  const int tid = threadIdx.x;
  const int wv = tid >> 6, l = tid & 63;
  const int g = l >> 4, lr = l & 15;
  const int n0 = blockIdx.x * 4;
  const int na = n0 + (wv >> 1) * 2;    // this wave's two n's
  const int nb = na + 1;
  const int sa = na - n0, sb = sa + 1;
  const int whalf = wv & 1;
  const int w0 = whalf * 32 + lr;       // w-tile 0 member for this lane
  const int w1p = w0 + 16;              // w-tile 1

  // ---- stage block-wide LDS state ----
  sG[tid] = G[tid]; sG[tid + 256] = G[tid + 256];
  sC[tid] = Cc[tid]; sC[tid + 256] = Cc[tid + 256];
  sGG[tid] = gg[tid]; sGG[tid + 256] = gg[tid + 256];
#pragma unroll
  for (int s = 0; s < 4; ++s) {
    sA[s][tid]       = Afull[(size_t)(n0 + s) * DD + tid];
    sA[s][tid + 256] = Afull[(size_t)(n0 + s) * DD + tid + 256];
    sQB[s][tid]       = q[(size_t)(n0 + s) * DD + tid] + b2[tid];
    sQB[s][tid + 256] = q[(size_t)(n0 + s) * DD + tid + 256] + b2[tid + 256];
  }
  // issue w2x chunk-0 prefetch (overlaps gelu generation)
#pragma unroll
  for (int j = 0; j < 8; ++j)
    async16(PW2X + (size_t)(j * 256 + tid) * 8, &sW[0][(j * 256 + wv * 64) * 8]);

  __syncthreads();

  // ---- LN1 scalars: 4 (n,w) combos ----
  float sqa = Sq[na], ssqa = SSq[na];
  float sqb = Sq[nb], ssqb = SSq[nb];
  float sc0 = Sc[w0], ssc0 = SSc[w0];
  float sc1 = Sc[w1p], ssc1 = SSc[w1p];
  float muA0 = (sqa + sc0) * (1.0f / 1024.0f);
  float rsA0 = rsqrtf((ssqa + ssc0) * (1.0f / 1024.0f) - muA0 * muA0 + 1e-5f);
  float muA1 = (sqa + sc1) * (1.0f / 1024.0f);
  float rsA1 = rsqrtf((ssqa + ssc1) * (1.0f / 1024.0f) - muA1 * muA1 + 1e-5f);
  float muB0 = (sqb + sc0) * (1.0f / 1024.0f);
  float rsB0 = rsqrtf((ssqb + ssc0) * (1.0f / 1024.0f) - muB0 * muB0 + 1e-5f);
  float muB1 = (sqb + sc1) * (1.0f / 1024.0f);
  float rsB1 = rsqrtf((ssqb + ssc1) * (1.0f / 1024.0f) - muB1 * muB1 + 1e-5f);
  float alA0 = rsA0, blA0 = -rsA0 * muA0;
  float alA1 = rsA1, blA1 = -rsA1 * muA1;
  float alB0 = rsB0, blB0 = -rsB0 * muB0;
  float alB1 = rsB1, blB1 = -rsB1 * muB1;

  // ---- gelu fragments: 4 sets (2 n x 2 w-tiles), MFMA B-operand layout ----
  short8 afA0[16], afA1[16], afB0[16], afB1[16];
  const unsigned short* pb0 = PBw + (size_t)(whalf * 2) * 16 * 512;
  const unsigned short* pb1 = PBw + (size_t)(whalf * 2 + 1) * 16 * 512;
#pragma unroll
  for (int t = 0; t < 16; ++t) {
    int kb = t * 32 + g * 8;
    f32x4 aA_0 = *(const f32x4*)&sA[sa][kb];
    f32x4 aA_1 = *(const f32x4*)&sA[sa][kb + 4];
    f32x4 aB_0 = *(const f32x4*)&sA[sb][kb];
    f32x4 aB_1 = *(const f32x4*)&sA[sb][kb + 4];
    f32x4 g0 = *(const f32x4*)&sG[kb];
    f32x4 g1v = *(const f32x4*)&sG[kb + 4];
    f32x4 c0 = *(const f32x4*)&sC[kb];
    f32x4 c1f = *(const f32x4*)&sC[kb + 4];
    ushort8 ub0 = *(const ushort8*)(pb0 + (size_t)(t * 64 + l) * 8);
    ushort8 ub1 = *(const ushort8*)(pb1 + (size_t)(t * 64 + l) * 8);
    float hA0[8], hA1[8], hB0[8], hB1[8];
#pragma unroll
    for (int i = 0; i < 4; ++i) {
      float b0lo = bf2f(ub0[i]), b1lo = bf2f(ub1[i]);
      float b0hi = bf2f(ub0[4 + i]), b1hi = bf2f(ub1[4 + i]);
      float inA0 = fmaf(blA0, g0[i], c0[i]);
      float inA1 = fmaf(blA1, g0[i], c0[i]);
      float inB0 = fmaf(blB0, g0[i], c0[i]);
      float inB1 = fmaf(blB1, g0[i], c0[i]);
      hA0[i] = gelu_f(fmaf(alA0, aA_0[i] + b0lo, inA0));
      hA1[i] = gelu_f(fmaf(alA1, aA_0[i] + b1lo, inA1));
      hB0[i] = gelu_f(fmaf(alB0, aB_0[i] + b0lo, inB0));
      hB1[i] = gelu_f(fmaf(alB1, aB_0[i] + b1lo, inB1));
      float jnA0 = fmaf(blA0, g1v[i], c1f[i]);
      float jnA1 = fmaf(blA1, g1v[i], c1f[i]);
      float jnB0 = fmaf(blB0, g1v[i], c1f[i]);
      float jnB1 = fmaf(blB1, g1v[i], c1f[i]);
      hA0[4 + i] = gelu_f(fmaf(alA0, aA_1[i] + b0hi, jnA0));
      hA1[4 + i] = gelu_f(fmaf(alA1, aA_1[i] + b1hi, jnA1));
      hB0[4 + i] = gelu_f(fmaf(alB0, aB_1[i] + b0hi, jnB0));
      hB1[4 + i] = gelu_f(fmaf(alB1, aB_1[i] + b1hi, jnB1));
    }
    union { short8 s; unsigned u[4]; } pA0, pA1, pB0, pB1;
    pA0.u[0] = cvtpk2(hA0[0], hA0[1]); pA0.u[1] = cvtpk2(hA0[2], hA0[3]);
    pA0.u[2] = cvtpk2(hA0[4], hA0[5]); pA0.u[3] = cvtpk2(hA0[6], hA0[7]);
    pA1.u[0] = cvtpk2(hA1[0], hA1[1]); pA1.u[1] = cvtpk2(hA1[2], hA1[3]);
    pA1.u[2] = cvtpk2(hA1[4], hA1[5]); pA1.u[3] = cvtpk2(hA1[6], hA1[7]);
    pB0.u[0] = cvtpk2(hB0[0], hB0[1]); pB0.u[1] = cvtpk2(hB0[2], hB0[3]);
    pB0.u[2] = cvtpk2(hB0[4], hB0[5]); pB0.u[3] = cvtpk2(hB0[6], hB0[7]);
    pB1.u[0] = cvtpk2(hB1[0], hB1[1]); pB1.u[1] = cvtpk2(hB1[2], hB1[3]);
    pB1.u[2] = cvtpk2(hB1[4], hB1[5]); pB1.u[3] = cvtpk2(hB1[6], hB1[7]);
    afA0[t] = pA0.s; afA1[t] = pA1.s;
    afB0[t] = pB0.s; afB1[t] = pB1.s;
  }

  float S2A0 = 0.f, S5A0 = 0.f, S2A1 = 0.f, S5A1 = 0.f;
  float S2B0 = 0.f, S5B0 = 0.f, S2B1 = 0.f, S5B1 = 0.f;
  float m6A0 = 0.f, m6A1 = 0.f, m6B0 = 0.f, m6B1 = 0.f;
  float v1A0 = 0.f, v3A0 = 0.f, v4A0 = 0.f;
  float v1A1 = 0.f, v3A1 = 0.f, v4A1 = 0.f;
  float v1B0 = 0.f, v3B0 = 0.f, v4B0 = 0.f;
  float v1B1 = 0.f, v3B1 = 0.f, v4B1 = 0.f;

  for (int cc = 0; cc < NCHUNK; ++cc) {
    __syncthreads();                    // chunk cc staged; prev chunk reads done
    if (cc < NCHUNK - 1) {
      const unsigned short* src = PW2X + (size_t)(cc + 1) * 16384;
      unsigned short* dst = sW[(cc + 1) & 1];
#pragma unroll
      for (int j = 0; j < 8; ++j)
        async16(src + (size_t)(j * 256 + tid) * 8, &dst[(j * 256 + wv * 64) * 8]);
    }
    const unsigned short* wbuf = sW[cc & 1];

    if (cc < 16) {
      f32x4 accA0_0 = {0,0,0,0}, accA0_1 = {0,0,0,0};
      f32x4 accA1_0 = {0,0,0,0}, accA1_1 = {0,0,0,0};
      f32x4 accB0_0 = {0,0,0,0}, accB0_1 = {0,0,0,0};
      f32x4 accB1_0 = {0,0,0,0}, accB1_1 = {0,0,0,0};
#pragma unroll
      for (int t = 0; t < 16; ++t) {
        short8 bf0 = *(const short8*)(wbuf + (size_t)((t * 64 + l) * 8));
        short8 bf1 = *(const short8*)(wbuf + (size_t)(((16 + t) * 64 + l) * 8));
        accA0_0 = __builtin_amdgcn_mfma_f32_16x16x32_bf16(bf0, afA0[t], accA0_0, 0, 0, 0);
        accA1_0 = __builtin_amdgcn_mfma_f32_16x16x32_bf16(bf0, afA1[t], accA1_0, 0, 0, 0);
        accB0_0 = __builtin_amdgcn_mfma_f32_16x16x32_bf16(bf0, afB0[t], accB0_0, 0, 0, 0);
        accB1_0 = __builtin_amdgcn_mfma_f32_16x16x32_bf16(bf0, afB1[t], accB1_0, 0, 0, 0);
        accA0_1 = __builtin_amdgcn_mfma_f32_16x16x32_bf16(bf1, afA0[t], accA0_1, 0, 0, 0);
        accA1_1 = __builtin_amdgcn_mfma_f32_16x16x32_bf16(bf1, afA1[t], accA1_1, 0, 0, 0);
        accB0_1 = __builtin_amdgcn_mfma_f32_16x16x32_bf16(bf1, afB0[t], accB0_1, 0, 0, 0);
        accB1_1 = __builtin_amdgcn_mfma_f32_16x16x32_bf16(bf1, afB1[t], accB1_1, 0, 0, 0);
      }
#pragma unroll
      for (int ct = 0; ct < 2; ++ct) {
        int cb = cc * 32 + ct * 16 + g * 4;
        f32x4 qbA = *(const f32x4*)&sQB[sa][cb];
        f32x4 qbB = *(const f32x4*)&sQB[sb][cb];
        f32x4 gg4 = *(const f32x4*)&sGG[cb];
        f32x4 aA0 = ct ? accA0_1 : accA0_0;
        f32x4 aA1 = ct ? accA1_1 : accA1_0;
        f32x4 aB0 = ct ? accB0_1 : accB0_0;
        f32x4 aB1 = ct ? accB1_1 : accB1_0;
#pragma unroll
        for (int r = 0; r < 4; ++r) {
          float y, y2;
          y = aA0[r] + qbA[r]; y2 = y * y; S2A0 += y2; S5A0 = fmaf(y2, gg4[r], S5A0);
          y = aA1[r] + qbA[r]; y2 = y * y; S2A1 += y2; S5A1 = fmaf(y2, gg4[r], S5A1);
          y = aB0[r] + qbB[r]; y2 = y * y; S2B0 += y2; S5B0 = fmaf(y2, gg4[r], S5B0);
          y = aB1[r] + qbB[r]; y2 = y * y; S2B1 += y2; S5B1 = fmaf(y2, gg4[r], S5B1);
        }
      }
    } else if (cc == 16 + whalf) {
      // M6 chunk holding this wave's w-range: diag dots for 4 sets
      f32x4 dA0 = {0,0,0,0}, dA1 = {0,0,0,0}, dB0 = {0,0,0,0}, dB1 = {0,0,0,0};
#pragma unroll
      for (int t = 0; t < 16; ++t) {
        short8 bf0 = *(const short8*)(wbuf + (size_t)((t * 64 + l) * 8));
        short8 bf1 = *(const short8*)(wbuf + (size_t)(((16 + t) * 64 + l) * 8));
        dA0 = __builtin_amdgcn_mfma_f32_16x16x32_bf16(bf0, afA0[t], dA0, 0, 0, 0);
        dB0 = __builtin_amdgcn_mfma_f32_16x16x32_bf16(bf0, afB0[t], dB0, 0, 0, 0);
        dA1 = __builtin_amdgcn_mfma_f32_16x16x32_bf16(bf1, afA1[t], dA1, 0, 0, 0);
        dB1 = __builtin_amdgcn_mfma_f32_16x16x32_bf16(bf1, afB1[t], dB1, 0, 0, 0);
      }
      int src = lr + ((lr >> 2) << 4);
      m6A0 = __shfl(sel4(dA0, lr & 3), src, 64);
      m6A1 = __shfl(sel4(dA1, lr & 3), src, 64);
      m6B0 = __shfl(sel4(dB0, lr & 3), src, 64);
      m6B1 = __shfl(sel4(dB1, lr & 3), src, 64);
    } else if (cc == 18) {
      // v-chunk: v1,v3,v4 at rows 0,1,2 of ct0
      f32x4 vA0 = {0,0,0,0}, vA1 = {0,0,0,0}, vB0 = {0,0,0,0}, vB1 = {0,0,0,0};
#pragma unroll
      for (int t = 0; t < 16; ++t) {
        short8 bf0 = *(const short8*)(wbuf + (size_t)((t * 64 + l) * 8));
        vA0 = __builtin_amdgcn_mfma_f32_16x16x32_bf16(bf0, afA0[t], vA0, 0, 0, 0);
        vA1 = __builtin_amdgcn_mfma_f32_16x16x32_bf16(bf0, afA1[t], vA1, 0, 0, 0);
        vB0 = __builtin_amdgcn_mfma_f32_16x16x32_bf16(bf0, afB0[t], vB0, 0, 0, 0);
        vB1 = __builtin_amdgcn_mfma_f32_16x16x32_bf16(bf0, afB1[t], vB1, 0, 0, 0);
      }
      v1A0 = __shfl(vA0[0], lr, 64); v3A0 = __shfl(vA0[1], lr, 64); v4A0 = __shfl(vA0[2], lr, 64);
      v1A1 = __shfl(vA1[0], lr, 64); v3A1 = __shfl(vA1[1], lr, 64); v4A1 = __shfl(vA1[2], lr, 64);
      v1B0 = __shfl(vB0[0], lr, 64); v3B0 = __shfl(vB0[1], lr, 64); v4B0 = __shfl(vB0[2], lr, 64);
      v1B1 = __shfl(vB1[0], lr, 64); v3B1 = __shfl(vB1[1], lr, 64); v4B1 = __shfl(vB1[2], lr, 64);
    }
  }

  // reduce quadratic sums over the 4 g-groups
  S2A0 += __shfl_xor(S2A0, 16, 64); S2A0 += __shfl_xor(S2A0, 32, 64);
  S5A0 += __shfl_xor(S5A0, 16, 64); S5A0 += __shfl_xor(S5A0, 32, 64);
  S2A1 += __shfl_xor(S2A1, 16, 64); S2A1 += __shfl_xor(S2A1, 32, 64);
  S5A1 += __shfl_xor(S5A1, 16, 64); S5A1 += __shfl_xor(S5A1, 32, 64);
  S2B0 += __shfl_xor(S2B0, 16, 64); S2B0 += __shfl_xor(S2B0, 32, 64);
  S5B0 += __shfl_xor(S5B0, 16, 64); S5B0 += __shfl_xor(S5B0, 32, 64);
  S2B1 += __shfl_xor(S2B1, 16, 64); S2B1 += __shfl_xor(S2B1, 32, 64);
  S5B1 += __shfl_xor(S5B1, 16, 64); S5B1 += __shfl_xor(S5B1, 32, 64);

  if (g == 0) {
    float sg2v = scal[0], sgbv = scal[1], sb2v = scal[2];
    float qbsA = qst[na * 4 + 0], qggA = qst[na * 4 + 1], qgbA = qst[na * 4 + 2];
    float qbsB = qst[nb * 4 + 0], qggB = qst[nb * 4 + 1], qgbB = qst[nb * 4 + 2];
#pragma unroll
    for (int e = 0; e < 4; ++e) {
      int n  = (e & 2) ? nb : na;
      int p  = e & 1;
      int w  = whalf * 32 + p * 16 + lr;
      float S1, S2, S3, S4, S5, S6d;
      if (e == 0)      { S1 = v1A0; S2 = S2A0; S3 = v3A0; S4 = v4A0; S5 = S5A0; S6d = m6A0; }
      else if (e == 1) { S1 = v1A1; S2 = S2A1; S3 = v3A1; S4 = v4A1; S5 = S5A1; S6d = m6A1; }
      else if (e == 2) { S1 = v1B0; S2 = S2B0; S3 = v3B0; S4 = v4B0; S5 = S5B0; S6d = m6B0; }
      else             { S1 = v1B1; S2 = S2B1; S3 = v3B1; S4 = v4B1; S5 = S5B1; S6d = m6B1; }
      float qbs  = (e & 2) ? qbsB : qbsA;
      float qggs = (e & 2) ? qggB : qggA;
      float qgbs = (e & 2) ? qgbB : qgbA;
      S1 += qbs; S3 += qggs; S4 += qgbs;
      float S6 = S6d + QC[(size_t)n * NWC + w] + c3v[w];
      float mu2 = S1 * (1.0f / 512.0f);
      float var2 = S2 * (1.0f / 512.0f) - mu2 * mu2;
      float rs2 = rsqrtf(var2 + 1e-5f);
      float n2 = rs2 * rs2 * (S5 - 2.f * mu2 * S3 + mu2 * mu2 * sg2v)
               + 2.f * rs2 * (S4 - mu2 * sgbv) + sb2v;
      float num = rs2 * (S6 - mu2 * c1v[w]) + c2v[w];
      out[(size_t)n * NWC + w] = 16.0f * num / fmaxf(sqrtf(fmaxf(n2, 0.f)), 1e-12f);
    }
  }
}

// ---------------- launch ----------------

extern "C" void kernel_launch(void* const* d_in, const int* in_sizes, int n_in,
                              void* d_out, int out_size, void* d_ws, size_t ws_size,
                              hipStream_t stream) {
  const float* q    = (const float*)d_in[0];
  const float* cm   = (const float*)d_in[1];
  const float* ln1w = (const float*)d_in[2];
  const float* ln1b = (const float*)d_in[3];
  const float* w1   = (const float*)d_in[4];
  const float* b1   = (const float*)d_in[5];
  const float* w2   = (const float*)d_in[6];
  const float* b2   = (const float*)d_in[7];
  const float* ln2w = (const float*)d_in[8];
  const float* ln2b = (const float*)d_in[9];
  float* out = (float*)d_out;

  char* p = (char*)d_ws;
  auto alloc = [&](size_t bytes) { char* r = p; p += (bytes + 255) & ~(size_t)255; return r; };
  float* A     = (float*)alloc((size_t)NQ * DD * 4);
  unsigned short* Bwb = (unsigned short*)alloc((size_t)NWC * DD * 2);
  float* G     = (float*)alloc(DD * 4);
  float* C     = (float*)alloc(DD * 4);
  float* Gp    = (float*)alloc((size_t)16 * DD * 4);
  float* Cp    = (float*)alloc((size_t)16 * DD * 4);
  float* Sq    = (float*)alloc(NQ * 4);
  float* SSq   = (float*)alloc(NQ * 4);
  float* Sc    = (float*)alloc(NWC * 4);
  float* SSc   = (float*)alloc(NWC * 4);
  float* cmhg  = (float*)alloc((size_t)NWC * DD * 4);
  float* c1    = (float*)alloc(NWC * 4);
  float* c2    = (float*)alloc(NWC * 4);
  float* c3    = (float*)alloc(NWC * 4);
  float* gg    = (float*)alloc(DD * 4);
  float* scal  = (float*)alloc(256);
  float* qst   = (float*)alloc((size_t)NQ * 4 * 4);
  float* QC    = (float*)alloc((size_t)NQ * NWC * 4);
  float* M6buf = (float*)alloc((size_t)DD * NWC * 4);
  float* Vbuf  = (float*)alloc((size_t)DD * 4 * 4);
  unsigned short* PW1T = (unsigned short*)alloc((size_t)DD * DD * 2);
  unsigned short* PW1B = (unsigned short*)alloc((size_t)DD * DD * 2);
  unsigned short* PCT  = (unsigned short*)alloc((size_t)DD * NWC * 2);
  unsigned short* PBw  = (unsigned short*)alloc((size_t)NWC * DD * 2);
  unsigned short* PW2X = (unsigned short*)alloc((size_t)NCHUNK * 16384 * 2);

  k_prep<<<401, 256, 0, stream>>>(q, cm, ln1w, ln1b, w1, w2, ln2w, ln2b, b2,
                                  Sq, SSq, qst, Sc, SSc, cmhg, c1, c2, c3,
                                  Gp, Cp, Vbuf, gg, scal);
  k_pack1<<<136, 512, 0, stream>>>(w1, ln1w, cmhg, PW1T, PW1B, PCT);
  k_gemms<<<304, 256, 0, stream>>>(q, cm, w2, PW1T, PW1B, PCT, A, Bwb, QC, M6buf);
  k_pack2<<<85, 512, 0, stream>>>(w2, M6buf, Vbuf, Bwb, Gp, Cp, b1, PW2X, PBw, G, C);
  k_main<<<512, 256, 0, stream>>>(A, PBw, G, C, q, b2, gg, qst, QC, c1, c2, c3,
                                  Sq, SSq, Sc, SSc, scal, PW2X, out);
}

// Round 5
// 139.159 us; speedup vs baseline: 1.3245x; 1.3245x over previous
//
#include <hip/hip_runtime.h>
#include <cstdint>
#include <cstddef>

// ---------------------------------------------------------------------------
// HierarchicalQueryMatcher, N=2048, W=64, D=512.
//   LN1(x)@w1+b1 = rs*(A[n,:]+B[w,:]) - rs*mu*G + C
//   h2 = gelu(h) @ w2 ; y = h2 + q[n] + b2
//   out = 16 * dot(LN2(y), cmhat)/max(||LN2(y)||,eps)
// Linear-in-h2 sums folded into extra GEMM cols (M6 = w2@cmhg^T, v1,v3,v4);
// quadratic sums (S2, S5) streamed in the MFMA epilogue.
// Round 5 k_main: 512 thr (8 waves, 2/SIMD), 3-buffer ring, prefetch depth 2,
// counted s_waitcnt vmcnt(4) + raw s_barrier (T3/T4), setprio around MFMA (T5).
// ---------------------------------------------------------------------------

#define NQ 2048
#define NWC 64
#define DD 512
#define NCHUNK 19

typedef __attribute__((ext_vector_type(8))) short short8;
typedef __attribute__((ext_vector_type(8))) unsigned short ushort8;
typedef __attribute__((ext_vector_type(4))) float f32x4;

__device__ __forceinline__ unsigned short f2bf(float f) {
  unsigned u = __float_as_uint(f);
  u += 0x7fffu + ((u >> 16) & 1u);
  return (unsigned short)(u >> 16);
}

__device__ __forceinline__ unsigned cvtpk2(float lo, float hi) {
  unsigned r;
  asm("v_cvt_pk_bf16_f32 %0, %1, %2" : "=v"(r) : "v"(lo), "v"(hi));
  return r;
}

__device__ __forceinline__ float bf2f(unsigned short u) {
  return __uint_as_float(((unsigned)u) << 16);
}

__device__ __forceinline__ float gelu_f(float h) {
  float h2 = h * h;
  float z2 = h * fmaf(h2, 0.10295890518f, 2.30221607f); // *log2(e)
  float e = exp2f(z2);
  return h * (e * __builtin_amdgcn_rcpf(e + 1.0f));
}

__device__ __forceinline__ float wred(float v) {
#pragma unroll
  for (int m = 1; m < 64; m <<= 1) v += __shfl_xor(v, m, 64);
  return v;
}

__device__ __forceinline__ float sel4(f32x4 v, int r) {
  float x = (r & 1) ? v[1] : v[0];
  float y = (r & 1) ? v[3] : v[2];
  return (r & 2) ? y : x;
}

// ---------------- k_prep: all O(N*D) precompute in one launch ----------------
__global__ __launch_bounds__(256) void k_prep(
    const float* __restrict__ q, const float* __restrict__ cm,
    const float* __restrict__ g1, const float* __restrict__ be1,
    const float* __restrict__ w1, const float* __restrict__ w2,
    const float* __restrict__ g2, const float* __restrict__ be2,
    const float* __restrict__ b2,
    float* __restrict__ Sq, float* __restrict__ SSq, float* __restrict__ qst,
    float* __restrict__ Sc, float* __restrict__ SSc, float* __restrict__ cmhg,
    float* __restrict__ c1, float* __restrict__ c2, float* __restrict__ c3,
    float* __restrict__ Gp, float* __restrict__ Cp, float* __restrict__ V,
    float* __restrict__ gg, float* __restrict__ scal) {
  const int b = blockIdx.x, tid = threadIdx.x;
  const int wv = tid >> 6, l = tid & 63;
  __shared__ float shr[3][4];
  __shared__ float s_inv;

  if (b < 256) {
    f32x4 b20 = *(const f32x4*)(b2 + l * 8);
    f32x4 b21 = *(const f32x4*)(b2 + l * 8 + 4);
    f32x4 g20 = *(const f32x4*)(g2 + l * 8);
    f32x4 g21 = *(const f32x4*)(g2 + l * 8 + 4);
    f32x4 e20 = *(const f32x4*)(be2 + l * 8);
    f32x4 e21 = *(const f32x4*)(be2 + l * 8 + 4);
#pragma unroll
    for (int rr = 0; rr < 2; ++rr) {
      int r = b * 8 + wv * 2 + rr;
      const float* row = q + (size_t)r * DD;
      f32x4 q0 = *(const f32x4*)(row + l * 8);
      f32x4 q1 = *(const f32x4*)(row + l * 8 + 4);
      float s0 = 0, s1 = 0, s2 = 0, s3 = 0, s4 = 0;
#pragma unroll
      for (int i = 0; i < 4; ++i) {
        float v = q0[i]; s0 += v; s1 = fmaf(v, v, s1);
        float qb = v + b20[i], g = g20[i];
        s2 += qb; s3 = fmaf(qb, g * g, s3); s4 = fmaf(qb, g * e20[i], s4);
        v = q1[i]; s0 += v; s1 = fmaf(v, v, s1);
        qb = v + b21[i]; g = g21[i];
        s2 += qb; s3 = fmaf(qb, g * g, s3); s4 = fmaf(qb, g * e21[i], s4);
      }
      s0 = wred(s0); s1 = wred(s1); s2 = wred(s2); s3 = wred(s3); s4 = wred(s4);
      if (l == 0) {
        Sq[r] = s0; SSq[r] = s1;
        qst[r * 4 + 0] = s2; qst[r * 4 + 1] = s3; qst[r * 4 + 2] = s4;
      }
    }
  } else if (b < 320) {
    int w = b - 256;
    const float* row = cm + (size_t)w * DD;
    float sm = 0.f, ss = 0.f;
    for (int c = tid; c < DD; c += 256) { float v = row[c]; sm += v; ss = fmaf(v, v, ss); }
    sm = wred(sm); ss = wred(ss);
    if (l == 0) { shr[0][wv] = sm; shr[1][wv] = ss; }
    __syncthreads();
    if (tid == 0) {
      float smt = shr[0][0] + shr[0][1] + shr[0][2] + shr[0][3];
      float sst = shr[1][0] + shr[1][1] + shr[1][2] + shr[1][3];
      Sc[w] = smt; SSc[w] = sst;
      s_inv = 1.0f / fmaxf(sqrtf(sst), 1e-12f);
    }
    __syncthreads();
    float inv = s_inv;
    float a = 0.f, bs = 0.f, d = 0.f;
    for (int c = tid; c < DD; c += 256) {
      float ch = row[c] * inv;
      float gv = g2[c];
      float gch = gv * ch;
      cmhg[(size_t)w * DD + c] = gch;
      a += gch;
      bs = fmaf(be2[c], ch, bs);
      d = fmaf(b2[c], gch, d);
    }
    a = wred(a); bs = wred(bs); d = wred(d);
    __syncthreads();
    if (l == 0) { shr[0][wv] = a; shr[1][wv] = bs; shr[2][wv] = d; }
    __syncthreads();
    if (tid == 0) {
      c1[w] = shr[0][0] + shr[0][1] + shr[0][2] + shr[0][3];
      c2[w] = shr[1][0] + shr[1][1] + shr[1][2] + shr[1][3];
      c3[w] = shr[2][0] + shr[2][1] + shr[2][2] + shr[2][3];
    }
  } else if (b < 336) {
    int bk = b - 320, k0 = bk * 64;
#pragma unroll
    for (int jh = 0; jh < 2; ++jh) {
      int j = tid + jh * 256;
      float g = 0.f, c = 0.f;
#pragma unroll 4
      for (int k = 0; k < 64; ++k) {
        float wv4 = w1[(size_t)(k0 + k) * DD + j];
        g = fmaf(g1[k0 + k], wv4, g);
        c = fmaf(be1[k0 + k], wv4, c);
      }
      Gp[(size_t)bk * DD + j] = g;
      Cp[(size_t)bk * DD + j] = c;
    }
  } else if (b < 400) {
    int bb = b - 336;
    f32x4 g20 = *(const f32x4*)(g2 + l * 8);
    f32x4 g21 = *(const f32x4*)(g2 + l * 8 + 4);
    f32x4 e20 = *(const f32x4*)(be2 + l * 8);
    f32x4 e21 = *(const f32x4*)(be2 + l * 8 + 4);
#pragma unroll
    for (int rr = 0; rr < 2; ++rr) {
      int k = bb * 8 + wv * 2 + rr;
      const float* row = w2 + (size_t)k * DD;
      f32x4 w0 = *(const f32x4*)(row + l * 8);
      f32x4 w1v = *(const f32x4*)(row + l * 8 + 4);
      float s1 = 0, s3 = 0, s4 = 0;
#pragma unroll
      for (int i = 0; i < 4; ++i) {
        float w = w0[i], g = g20[i];
        s1 += w; s3 = fmaf(w, g * g, s3); s4 = fmaf(w, g * e20[i], s4);
        w = w1v[i]; g = g21[i];
        s1 += w; s3 = fmaf(w, g * g, s3); s4 = fmaf(w, g * e21[i], s4);
      }
      s1 = wred(s1); s3 = wred(s3); s4 = wred(s4);
      if (l == 0) {
        V[k * 4 + 0] = s1; V[k * 4 + 1] = s3; V[k * 4 + 2] = s4; V[k * 4 + 3] = 0.f;
      }
    }
  } else {
    float a0 = 0, a1 = 0, a2 = 0;
    for (int c = tid; c < DD; c += 256) {
      float g = g2[c], be = be2[c];
      gg[c] = g * g;
      a0 = fmaf(g, g, a0); a1 = fmaf(g, be, a1); a2 = fmaf(be, be, a2);
    }
    a0 = wred(a0); a1 = wred(a1); a2 = wred(a2);
    if (l == 0) { shr[0][wv] = a0; shr[1][wv] = a1; shr[2][wv] = a2; }
    __syncthreads();
    if (tid == 0) {
      scal[0] = shr[0][0] + shr[0][1] + shr[0][2] + shr[0][3];
      scal[1] = shr[1][0] + shr[1][1] + shr[1][2] + shr[1][3];
      scal[2] = shr[2][0] + shr[2][1] + shr[2][2] + shr[2][3];
    }
  }
}

// ---------------- k_pack1: PW1T + PW1B + PCT ----------------
__global__ __launch_bounds__(512) void k_pack1(
    const float* __restrict__ w1, const float* __restrict__ ln1w,
    const float* __restrict__ cmhg,
    unsigned short* __restrict__ PW1T, unsigned short* __restrict__ PW1B,
    unsigned short* __restrict__ PCT) {
  int b = blockIdx.x;
  if (b < 128) {
    int roff = (b < 64) ? 0 : 512;
    unsigned short* out = (b < 64) ? PW1T : PW1B;
    int tid = (b & 63) * 512 + threadIdx.x;
    int l = tid & 63, t = (tid >> 6) & 15, ct = tid >> 10, g = l >> 4;
    int col = (ct << 4) + (l & 15);
    ushort8 o;
#pragma unroll
    for (int i = 0; i < 8; ++i) {
      int k = t * 32 + g * 8 + i;
      o[i] = f2bf(w1[(size_t)(roff + k) * DD + col] * ln1w[roff + k]);
    }
    *(ushort8*)(out + (size_t)tid * 8) = o;
  } else {
    int tid = (b - 128) * 512 + threadIdx.x;
    int l = tid & 63, t = (tid >> 6) & 15, g = l >> 4;
    int col = ((tid >> 10) << 4) + (l & 15);
    ushort8 o;
#pragma unroll
    for (int i = 0; i < 8; ++i) {
      int k = t * 32 + g * 8 + i;
      o[i] = f2bf(cmhg[(size_t)col * DD + k]);
    }
    *(ushort8*)(PCT + (size_t)tid * 8) = o;
  }
}

// ---------------- k_gemms: 4 GEMM jobs in one dispatch ----------------
__global__ __launch_bounds__(256) void k_gemms(
    const float* __restrict__ q, const float* __restrict__ cm,
    const float* __restrict__ w2,
    const unsigned short* __restrict__ PW1T, const unsigned short* __restrict__ PW1B,
    const unsigned short* __restrict__ PCT,
    float* __restrict__ A, unsigned short* __restrict__ Bwb,
    float* __restrict__ QC, float* __restrict__ M6) {
  int b = blockIdx.x;
  const float* X; const unsigned short* PW; void* Out;
  int bx, by, ostride, obf;
  if (b < 256)      { X = q;  PW = PW1T; Out = A;    bx = b & 7;   by = b >> 3;  ostride = DD;  obf = 0; }
  else if (b < 264) { X = cm; PW = PW1B; Out = Bwb;  bx = b - 256; by = 0;       ostride = DD;  obf = 1; }
  else if (b < 296) { X = q;  PW = PCT;  Out = QC;   bx = 0;       by = b - 264; ostride = NWC; obf = 0; }
  else              { X = w2; PW = PCT;  Out = M6;   bx = 0;       by = b - 296; ostride = NWC; obf = 0; }

  int l = threadIdx.x & 63;
  int wv = threadIdx.x >> 6;
  int lr = l & 15, g = l >> 4;
  int r0 = by * 64 + wv * 16;
  int cb0 = bx * 4;
  f32x4 acc[4] = {{0,0,0,0},{0,0,0,0},{0,0,0,0},{0,0,0,0}};
  const float* xrow = X + (size_t)(r0 + lr) * DD;
#pragma unroll
  for (int t = 0; t < 16; ++t) {
    int kb = t * 32 + g * 8;
    f32x4 x0 = *(const f32x4*)(xrow + kb);
    f32x4 x1 = *(const f32x4*)(xrow + kb + 4);
    union { short8 s; unsigned u[4]; } af;
    af.u[0] = cvtpk2(x0[0], x0[1]);
    af.u[1] = cvtpk2(x0[2], x0[3]);
    af.u[2] = cvtpk2(x1[0], x1[1]);
    af.u[3] = cvtpk2(x1[2], x1[3]);
#pragma unroll
    for (int c = 0; c < 4; ++c) {
      short8 bf = *(const short8*)(PW + (size_t)(((cb0 + c) * 16 + t) * 64 + l) * 8);
      acc[c] = __builtin_amdgcn_mfma_f32_16x16x32_bf16(af.s, bf, acc[c], 0, 0, 0);
    }
  }
#pragma unroll
  for (int c = 0; c < 4; ++c)
#pragma unroll
    for (int r = 0; r < 4; ++r) {
      size_t idx = (size_t)(r0 + g * 4 + r) * ostride + (cb0 + c) * 16 + lr;
      float v = acc[c][r];
      if (obf) ((unsigned short*)Out)[idx] = f2bf(v);
      else     ((float*)Out)[idx] = v;
    }
}

// ---------------- k_pack2: PW2X + PBw + G/C reduce ----------------
__global__ __launch_bounds__(512) void k_pack2(
    const float* __restrict__ w2, const float* __restrict__ M6,
    const float* __restrict__ V, const unsigned short* __restrict__ Bwb,
    const float* __restrict__ Gp, const float* __restrict__ Cp,
    const float* __restrict__ b1,
    unsigned short* __restrict__ PW2X, unsigned short* __restrict__ PBw,
    float* __restrict__ G, float* __restrict__ C) {
  int b = blockIdx.x;
  if (b < 76) {
    int tid = b * 512 + threadIdx.x;
    int l = tid & 63, t = (tid >> 6) & 15, ct = tid >> 10, g = l >> 4;
    int col = (ct << 4) + (l & 15);
    ushort8 o;
#pragma unroll
    for (int i = 0; i < 8; ++i) {
      int k = t * 32 + g * 8 + i;
      float v;
      if (col < 512)      v = w2[(size_t)k * DD + col];
      else if (col < 576) v = M6[(size_t)k * 64 + (col - 512)];
      else { int cv = col - 576; v = (cv < 3) ? V[k * 4 + cv] : 0.f; }
      o[i] = f2bf(v);
    }
    *(ushort8*)(PW2X + (size_t)tid * 8) = o;
  } else if (b < 84) {
    int tid = (b - 76) * 512 + threadIdx.x;
    int l = tid & 63, t = (tid >> 6) & 15, wt = tid >> 10;
    ushort8 o;
#pragma unroll
    for (int i = 0; i < 8; ++i)
      o[i] = Bwb[(size_t)(wt * 16 + (l & 15)) * DD + t * 32 + (l >> 4) * 8 + i];
    *(ushort8*)(PBw + (size_t)tid * 8) = o;
  } else {
    int c = threadIdx.x;
    float g = 0.f, cc = 0.f;
#pragma unroll
    for (int p = 0; p < 16; ++p) { g += Gp[p * DD + c]; cc += Cp[p * DD + c]; }
    G[c] = g; C[c] = cc + b1[c];
  }
}

// ---------------- fused main kernel: counted-vmcnt 3-buffer pipeline ----------

__device__ __forceinline__ void async16(const void* g, void* lds) {
  __builtin_amdgcn_global_load_lds(
      (const __attribute__((address_space(1))) void*)(uintptr_t)g,
      (__attribute__((address_space(3))) void*)(unsigned int)(uintptr_t)lds,
      16, 0, 0);
}

__global__ __launch_bounds__(512, 2) void k_main(
    const float* __restrict__ Afull, const unsigned short* __restrict__ PBw,
    const float* __restrict__ G, const float* __restrict__ Cc,
    const float* __restrict__ q, const float* __restrict__ b2,
    const float* __restrict__ gg, const float* __restrict__ qst,
    const float* __restrict__ QC, const float* __restrict__ c1v,
    const float* __restrict__ c2v, const float* __restrict__ c3v,
    const float* __restrict__ Sq, const float* __restrict__ SSq,
    const float* __restrict__ Sc, const float* __restrict__ SSc,
    const float* __restrict__ scal, const unsigned short* __restrict__ PW2X,
    float* __restrict__ out) {

  __shared__ __align__(16) float sG[DD], sC[DD], sGG[DD];
  __shared__ __align__(16) float sA[4][DD], sQB[4][DD];
  __shared__ __align__(16) unsigned short sW[3][16384];   // 3x32KB chunk ring

  const int tid = threadIdx.x;
  const int wv = tid >> 6, l = tid & 63;
  const int g = l >> 4, lr = l & 15;
  const int n0 = blockIdx.x * 4;
  const int sub = wv >> 1;             // which n of the 4
  const int n = n0 + sub;
  const int whalf = wv & 1;
  const int w0 = whalf * 32 + lr;
  const int w1p = w0 + 16;

  // ---- stage block-wide LDS state (512 threads cover 512 cols) ----
  sG[tid] = G[tid]; sC[tid] = Cc[tid]; sGG[tid] = gg[tid];
#pragma unroll
  for (int s = 0; s < 4; ++s) {
    sA[s][tid]  = Afull[(size_t)(n0 + s) * DD + tid];
    sQB[s][tid] = q[(size_t)(n0 + s) * DD + tid] + b2[tid];
  }
  __syncthreads();

  // issue prefetch of chunks 0,1 (hidden under the gelu phase)
#pragma unroll
  for (int c = 0; c < 2; ++c)
#pragma unroll
    for (int j = 0; j < 4; ++j)
      async16(PW2X + (size_t)c * 16384 + (size_t)(j * 512 + tid) * 8,
              &sW[c][(j * 512 + wv * 64) * 8]);

  // ---- LN1 scalars for this lane's two (n,w) pairs ----
  float sqn = Sq[n], ssqn = SSq[n];
  float mu0 = (sqn + Sc[w0]) * (1.0f / 1024.0f);
  float rs0 = rsqrtf((ssqn + SSc[w0]) * (1.0f / 1024.0f) - mu0 * mu0 + 1e-5f);
  float mu1 = (sqn + Sc[w1p]) * (1.0f / 1024.0f);
  float rs1 = rsqrtf((ssqn + SSc[w1p]) * (1.0f / 1024.0f) - mu1 * mu1 + 1e-5f);
  float al0 = rs0, bl0 = -rs0 * mu0;
  float al1 = rs1, bl1 = -rs1 * mu1;

  // ---- gelu fragments straight into MFMA B-operand layout ----
  short8 af0[16], af1[16];
  const unsigned short* pb0 = PBw + (size_t)(whalf * 2) * 16 * 512;
  const unsigned short* pb1 = PBw + (size_t)(whalf * 2 + 1) * 16 * 512;
#pragma unroll
  for (int t = 0; t < 16; ++t) {
    int kb = t * 32 + g * 8;
    f32x4 a0 = *(const f32x4*)&sA[sub][kb];
    f32x4 a1 = *(const f32x4*)&sA[sub][kb + 4];
    f32x4 g0 = *(const f32x4*)&sG[kb];
    f32x4 g1v = *(const f32x4*)&sG[kb + 4];
    f32x4 c0 = *(const f32x4*)&sC[kb];
    f32x4 c1f = *(const f32x4*)&sC[kb + 4];
    ushort8 ub0 = *(const ushort8*)(pb0 + (size_t)(t * 64 + l) * 8);
    ushort8 ub1 = *(const ushort8*)(pb1 + (size_t)(t * 64 + l) * 8);
    float hA[8], hB[8];
#pragma unroll
    for (int i = 0; i < 4; ++i) {
      float in0 = fmaf(bl0, g0[i], c0[i]);
      float in1 = fmaf(bl1, g0[i], c0[i]);
      hA[i] = gelu_f(fmaf(al0, a0[i] + bf2f(ub0[i]), in0));
      hB[i] = gelu_f(fmaf(al1, a0[i] + bf2f(ub1[i]), in1));
      float jn0 = fmaf(bl0, g1v[i], c1f[i]);
      float jn1 = fmaf(bl1, g1v[i], c1f[i]);
      hA[4 + i] = gelu_f(fmaf(al0, a1[i] + bf2f(ub0[4 + i]), jn0));
      hB[4 + i] = gelu_f(fmaf(al1, a1[i] + bf2f(ub1[4 + i]), jn1));
    }
    union { short8 s; unsigned u[4]; } pa, pb;
    pa.u[0] = cvtpk2(hA[0], hA[1]); pa.u[1] = cvtpk2(hA[2], hA[3]);
    pa.u[2] = cvtpk2(hA[4], hA[5]); pa.u[3] = cvtpk2(hA[6], hA[7]);
    pb.u[0] = cvtpk2(hB[0], hB[1]); pb.u[1] = cvtpk2(hB[2], hB[3]);
    pb.u[2] = cvtpk2(hB[4], hB[5]); pb.u[3] = cvtpk2(hB[6], hB[7]);
    af0[t] = pa.s; af1[t] = pb.s;
  }

  float S20 = 0.f, S50 = 0.f, S21 = 0.f, S51 = 0.f;
  float m6d0 = 0.f, m6d1 = 0.f;
  float v1d0 = 0.f, v3d0 = 0.f, v4d0 = 0.f;
  float v1d1 = 0.f, v3d1 = 0.f, v4d1 = 0.f;

  for (int cc = 0; cc < NCHUNK; ++cc) {
    // counted waits: chunk cc's 4 loads landed; cc+1's 4 stay in flight.
    if (cc < NCHUNK - 1) asm volatile("s_waitcnt vmcnt(4)" ::: "memory");
    else                 asm volatile("s_waitcnt vmcnt(0)" ::: "memory");
    asm volatile("s_waitcnt lgkmcnt(0)" ::: "memory");
    __builtin_amdgcn_s_barrier();      // all waves: cc landed, cc-1 reads done
    if (cc + 2 < NCHUNK) {             // prefetch depth 2 into ring slot
      const unsigned short* src = PW2X + (size_t)(cc + 2) * 16384;
      unsigned short* dst = sW[(cc + 2) % 3];
#pragma unroll
      for (int j = 0; j < 4; ++j)
        async16(src + (size_t)(j * 512 + tid) * 8, &dst[(j * 512 + wv * 64) * 8]);
    }
    const unsigned short* wbuf = sW[cc % 3];

    if (cc < 16) {
      f32x4 acc00 = {0,0,0,0}, acc01 = {0,0,0,0}, acc10 = {0,0,0,0}, acc11 = {0,0,0,0};
      __builtin_amdgcn_s_setprio(1);
#pragma unroll
      for (int t = 0; t < 16; ++t) {
        short8 bf0 = *(const short8*)(wbuf + (size_t)((t * 64 + l) * 8));
        short8 bf1 = *(const short8*)(wbuf + (size_t)(((16 + t) * 64 + l) * 8));
        acc00 = __builtin_amdgcn_mfma_f32_16x16x32_bf16(bf0, af0[t], acc00, 0, 0, 0);
        acc10 = __builtin_amdgcn_mfma_f32_16x16x32_bf16(bf0, af1[t], acc10, 0, 0, 0);
        acc01 = __builtin_amdgcn_mfma_f32_16x16x32_bf16(bf1, af0[t], acc01, 0, 0, 0);
        acc11 = __builtin_amdgcn_mfma_f32_16x16x32_bf16(bf1, af1[t], acc11, 0, 0, 0);
      }
      __builtin_amdgcn_s_setprio(0);
#pragma unroll
      for (int ct = 0; ct < 2; ++ct) {
        int cb = cc * 32 + ct * 16 + g * 4;
        f32x4 qb4 = *(const f32x4*)&sQB[sub][cb];
        f32x4 gg4 = *(const f32x4*)&sGG[cb];
        f32x4 aAv = ct ? acc01 : acc00;
        f32x4 aBv = ct ? acc11 : acc10;
#pragma unroll
        for (int r = 0; r < 4; ++r) {
          float y = aAv[r] + qb4[r];
          float y2 = y * y;
          S20 += y2; S50 = fmaf(y2, gg4[r], S50);
          float z = aBv[r] + qb4[r];
          float z2 = z * z;
          S21 += z2; S51 = fmaf(z2, gg4[r], S51);
        }
      }
    } else if (cc == 16 + whalf) {
      f32x4 acc00 = {0,0,0,0}, acc11 = {0,0,0,0};
      __builtin_amdgcn_s_setprio(1);
#pragma unroll
      for (int t = 0; t < 16; ++t) {
        short8 bf0 = *(const short8*)(wbuf + (size_t)((t * 64 + l) * 8));
        short8 bf1 = *(const short8*)(wbuf + (size_t)(((16 + t) * 64 + l) * 8));
        acc00 = __builtin_amdgcn_mfma_f32_16x16x32_bf16(bf0, af0[t], acc00, 0, 0, 0);
        acc11 = __builtin_amdgcn_mfma_f32_16x16x32_bf16(bf1, af1[t], acc11, 0, 0, 0);
      }
      __builtin_amdgcn_s_setprio(0);
      float d0 = sel4(acc00, lr & 3);
      float d1 = sel4(acc11, lr & 3);
      int src = lr + ((lr >> 2) << 4);
      m6d0 = __shfl(d0, src, 64);
      m6d1 = __shfl(d1, src, 64);
    } else if (cc == 18) {
      f32x4 acc00 = {0,0,0,0}, acc10 = {0,0,0,0};
      __builtin_amdgcn_s_setprio(1);
#pragma unroll
      for (int t = 0; t < 16; ++t) {
        short8 bf0 = *(const short8*)(wbuf + (size_t)((t * 64 + l) * 8));
        acc00 = __builtin_amdgcn_mfma_f32_16x16x32_bf16(bf0, af0[t], acc00, 0, 0, 0);
        acc10 = __builtin_amdgcn_mfma_f32_16x16x32_bf16(bf0, af1[t], acc10, 0, 0, 0);
      }
      __builtin_amdgcn_s_setprio(0);
      v1d0 = __shfl(acc00[0], lr, 64);
      v3d0 = __shfl(acc00[1], lr, 64);
      v4d0 = __shfl(acc00[2], lr, 64);
      v1d1 = __shfl(acc10[0], lr, 64);
      v3d1 = __shfl(acc10[1], lr, 64);
      v4d1 = __shfl(acc10[2], lr, 64);
    }
  }

  S20 += __shfl_xor(S20, 16, 64); S20 += __shfl_xor(S20, 32, 64);
  S50 += __shfl_xor(S50, 16, 64); S50 += __shfl_xor(S50, 32, 64);
  S21 += __shfl_xor(S21, 16, 64); S21 += __shfl_xor(S21, 32, 64);
  S51 += __shfl_xor(S51, 16, 64); S51 += __shfl_xor(S51, 32, 64);

  if (g == 0) {
    float sg2v = scal[0], sgbv = scal[1], sb2v = scal[2];
    float qbs = qst[n * 4 + 0], qggs = qst[n * 4 + 1], qgbs = qst[n * 4 + 2];
#pragma unroll
    for (int p = 0; p < 2; ++p) {
      int w = whalf * 32 + p * 16 + lr;
      float S1 = (p ? v1d1 : v1d0) + qbs;
      float S2 = (p ? S21 : S20);
      float S3 = (p ? v3d1 : v3d0) + qggs;
      float S4 = (p ? v4d1 : v4d0) + qgbs;
      float S5 = (p ? S51 : S50);
      float S6 = (p ? m6d1 : m6d0) + QC[(size_t)n * NWC + w] + c3v[w];
      float mu2 = S1 * (1.0f / 512.0f);
      float var2 = S2 * (1.0f / 512.0f) - mu2 * mu2;
      float rs2 = rsqrtf(var2 + 1e-5f);
      float n2 = rs2 * rs2 * (S5 - 2.f * mu2 * S3 + mu2 * mu2 * sg2v)
               + 2.f * rs2 * (S4 - mu2 * sgbv) + sb2v;
      float num = rs2 * (S6 - mu2 * c1v[w]) + c2v[w];
      out[(size_t)n * NWC + w] = 16.0f * num / fmaxf(sqrtf(fmaxf(n2, 0.f)), 1e-12f);
    }
  }
}

// ---------------- launch ----------------

extern "C" void kernel_launch(void* const* d_in, const int* in_sizes, int n_in,
                              void* d_out, int out_size, void* d_ws, size_t ws_size,
                              hipStream_t stream) {
  const float* q    = (const float*)d_in[0];
  const float* cm   = (const float*)d_in[1];
  const float* ln1w = (const float*)d_in[2];
  const float* ln1b = (const float*)d_in[3];
  const float* w1   = (const float*)d_in[4];
  const float* b1   = (const float*)d_in[5];
  const float* w2   = (const float*)d_in[6];
  const float* b2   = (const float*)d_in[7];
  const float* ln2w = (const float*)d_in[8];
  const float* ln2b = (const float*)d_in[9];
  float* out = (float*)d_out;

  char* p = (char*)d_ws;
  auto alloc = [&](size_t bytes) { char* r = p; p += (bytes + 255) & ~(size_t)255; return r; };
  float* A     = (float*)alloc((size_t)NQ * DD * 4);
  unsigned short* Bwb = (unsigned short*)alloc((size_t)NWC * DD * 2);
  float* G     = (float*)alloc(DD * 4);
  float* C     = (float*)alloc(DD * 4);
  float* Gp    = (float*)alloc((size_t)16 * DD * 4);
  float* Cp    = (float*)alloc((size_t)16 * DD * 4);
  float* Sq    = (float*)alloc(NQ * 4);
  float* SSq   = (float*)alloc(NQ * 4);
  float* Sc    = (float*)alloc(NWC * 4);
  float* SSc   = (float*)alloc(NWC * 4);
  float* cmhg  = (float*)alloc((size_t)NWC * DD * 4);
  float* c1    = (float*)alloc(NWC * 4);
  float* c2    = (float*)alloc(NWC * 4);
  float* c3    = (float*)alloc(NWC * 4);
  float* gg    = (float*)alloc(DD * 4);
  float* scal  = (float*)alloc(256);
  float* qst   = (float*)alloc((size_t)NQ * 4 * 4);
  float* QC    = (float*)alloc((size_t)NQ * NWC * 4);
  float* M6buf = (float*)alloc((size_t)DD * NWC * 4);
  float* Vbuf  = (float*)alloc((size_t)DD * 4 * 4);
  unsigned short* PW1T = (unsigned short*)alloc((size_t)DD * DD * 2);
  unsigned short* PW1B = (unsigned short*)alloc((size_t)DD * DD * 2);
  unsigned short* PCT  = (unsigned short*)alloc((size_t)DD * NWC * 2);
  unsigned short* PBw  = (unsigned short*)alloc((size_t)NWC * DD * 2);
  unsigned short* PW2X = (unsigned short*)alloc((size_t)NCHUNK * 16384 * 2);

  k_prep<<<401, 256, 0, stream>>>(q, cm, ln1w, ln1b, w1, w2, ln2w, ln2b, b2,
                                  Sq, SSq, qst, Sc, SSc, cmhg, c1, c2, c3,
                                  Gp, Cp, Vbuf, gg, scal);
  k_pack1<<<136, 512, 0, stream>>>(w1, ln1w, cmhg, PW1T, PW1B, PCT);
  k_gemms<<<304, 256, 0, stream>>>(q, cm, w2, PW1T, PW1B, PCT, A, Bwb, QC, M6buf);
  k_pack2<<<85, 512, 0, stream>>>(w2, M6buf, Vbuf, Bwb, Gp, Cp, b1, PW2X, PBw, G, C);
  k_main<<<512, 512, 0, stream>>>(A, PBw, G, C, q, b2, gg, qst, QC, c1, c2, c3,
                                  Sq, SSq, Sc, SSc, scal, PW2X, out);
}

// Round 6
// 124.452 us; speedup vs baseline: 1.4811x; 1.1182x over previous
//
#include <hip/hip_runtime.h>
#include <cstdint>
#include <cstddef>

// ---------------------------------------------------------------------------
// HierarchicalQueryMatcher, N=2048, W=64, D=512.
//   LN1(x)@w1+b1 = rs*(A[n,:]+B[w,:]) - rs*mu*G + C
//   h2 = gelu(h) @ w2 ; y = h2 + q[n] + b2
//   out = 16 * dot(LN2(y), cmhat)/max(||LN2(y)||,eps)
// Linear-in-h2 sums folded into extra GEMM cols (M6 = w2@cmhg^T, v1,v3,v4);
// quadratic sums (S2, S5) streamed in the MFMA epilogue.
// Round 6: h2-GEMM in INT8 (mfma_i32_16x16x64_i8, 2x rate, half LDS bytes).
//   W2X quantized per-column (scale s_c), gelu quantized with fixed s_a=4/127.
//   h2 = i32acc * (s_a*s_c). Pipe model: LDS 49->24us, MFMA 39->21us.
// ---------------------------------------------------------------------------

#define NQ 2048
#define NWC 64
#define DD 512
#define NCHUNK 19
#define SA_CONST (4.0f / 127.0f)

typedef __attribute__((ext_vector_type(8))) short short8;
typedef __attribute__((ext_vector_type(8))) unsigned short ushort8;
typedef __attribute__((ext_vector_type(4))) float f32x4;
typedef __attribute__((ext_vector_type(4))) int i32v4;
typedef __attribute__((ext_vector_type(4))) unsigned u32x4;

__device__ __forceinline__ unsigned short f2bf(float f) {
  unsigned u = __float_as_uint(f);
  u += 0x7fffu + ((u >> 16) & 1u);
  return (unsigned short)(u >> 16);
}

__device__ __forceinline__ unsigned cvtpk2(float lo, float hi) {
  unsigned r;
  asm("v_cvt_pk_bf16_f32 %0, %1, %2" : "=v"(r) : "v"(lo), "v"(hi));
  return r;
}

__device__ __forceinline__ float bf2f(unsigned short u) {
  return __uint_as_float(((unsigned)u) << 16);
}

// gelu(h)*31.75 (i8 domain), clamped. tanh-approx, sigmoid form (1 mul saved).
__device__ __forceinline__ float gelu31(float h) {
  float h2 = h * h;
  float zn = h * fmaf(h2, -0.10295890518f, -2.30221607f); // -z*log2(e)
  float t = exp2f(zn);
  float r = __builtin_amdgcn_rcpf(1.0f + t);
  float g = (h * 31.75f) * r;
  return fminf(fmaxf(g, -127.0f), 127.0f);
}

__device__ __forceinline__ unsigned pk4i8(float a, float b, float c, float d) {
  int ia = (int)rintf(a), ib = (int)rintf(b), ic = (int)rintf(c), id = (int)rintf(d);
  return (unsigned)(ia & 255) | ((unsigned)(ib & 255) << 8) |
         ((unsigned)(ic & 255) << 16) | ((unsigned)(id & 255) << 24);
}

__device__ __forceinline__ float wred(float v) {
#pragma unroll
  for (int m = 1; m < 64; m <<= 1) v += __shfl_xor(v, m, 64);
  return v;
}

__device__ __forceinline__ int sel4i(i32v4 v, int r) {
  int x = (r & 1) ? v[1] : v[0];
  int y = (r & 1) ? v[3] : v[2];
  return (r & 2) ? y : x;
}

// ---------------- k_prep: all O(N*D) precompute in one launch ----------------
__global__ __launch_bounds__(256) void k_prep(
    const float* __restrict__ q, const float* __restrict__ cm,
    const float* __restrict__ g1, const float* __restrict__ be1,
    const float* __restrict__ w1, const float* __restrict__ w2,
    const float* __restrict__ g2, const float* __restrict__ be2,
    const float* __restrict__ b2,
    float* __restrict__ Sq, float* __restrict__ SSq, float* __restrict__ qst,
    float* __restrict__ Sc, float* __restrict__ SSc, float* __restrict__ cmhg,
    float* __restrict__ c1, float* __restrict__ c2, float* __restrict__ c3,
    float* __restrict__ Gp, float* __restrict__ Cp, float* __restrict__ V,
    float* __restrict__ gg, float* __restrict__ scal) {
  const int b = blockIdx.x, tid = threadIdx.x;
  const int wv = tid >> 6, l = tid & 63;
  __shared__ float shr[3][4];
  __shared__ float s_inv;

  if (b < 256) {
    f32x4 b20 = *(const f32x4*)(b2 + l * 8);
    f32x4 b21 = *(const f32x4*)(b2 + l * 8 + 4);
    f32x4 g20 = *(const f32x4*)(g2 + l * 8);
    f32x4 g21 = *(const f32x4*)(g2 + l * 8 + 4);
    f32x4 e20 = *(const f32x4*)(be2 + l * 8);
    f32x4 e21 = *(const f32x4*)(be2 + l * 8 + 4);
#pragma unroll
    for (int rr = 0; rr < 2; ++rr) {
      int r = b * 8 + wv * 2 + rr;
      const float* row = q + (size_t)r * DD;
      f32x4 q0 = *(const f32x4*)(row + l * 8);
      f32x4 q1 = *(const f32x4*)(row + l * 8 + 4);
      float s0 = 0, s1 = 0, s2 = 0, s3 = 0, s4 = 0;
#pragma unroll
      for (int i = 0; i < 4; ++i) {
        float v = q0[i]; s0 += v; s1 = fmaf(v, v, s1);
        float qb = v + b20[i], g = g20[i];
        s2 += qb; s3 = fmaf(qb, g * g, s3); s4 = fmaf(qb, g * e20[i], s4);
        v = q1[i]; s0 += v; s1 = fmaf(v, v, s1);
        qb = v + b21[i]; g = g21[i];
        s2 += qb; s3 = fmaf(qb, g * g, s3); s4 = fmaf(qb, g * e21[i], s4);
      }
      s0 = wred(s0); s1 = wred(s1); s2 = wred(s2); s3 = wred(s3); s4 = wred(s4);
      if (l == 0) {
        Sq[r] = s0; SSq[r] = s1;
        qst[r * 4 + 0] = s2; qst[r * 4 + 1] = s3; qst[r * 4 + 2] = s4;
      }
    }
  } else if (b < 320) {
    int w = b - 256;
    const float* row = cm + (size_t)w * DD;
    float sm = 0.f, ss = 0.f;
    for (int c = tid; c < DD; c += 256) { float v = row[c]; sm += v; ss = fmaf(v, v, ss); }
    sm = wred(sm); ss = wred(ss);
    if (l == 0) { shr[0][wv] = sm; shr[1][wv] = ss; }
    __syncthreads();
    if (tid == 0) {
      float smt = shr[0][0] + shr[0][1] + shr[0][2] + shr[0][3];
      float sst = shr[1][0] + shr[1][1] + shr[1][2] + shr[1][3];
      Sc[w] = smt; SSc[w] = sst;
      s_inv = 1.0f / fmaxf(sqrtf(sst), 1e-12f);
    }
    __syncthreads();
    float inv = s_inv;
    float a = 0.f, bs = 0.f, d = 0.f;
    for (int c = tid; c < DD; c += 256) {
      float ch = row[c] * inv;
      float gv = g2[c];
      float gch = gv * ch;
      cmhg[(size_t)w * DD + c] = gch;
      a += gch;
      bs = fmaf(be2[c], ch, bs);
      d = fmaf(b2[c], gch, d);
    }
    a = wred(a); bs = wred(bs); d = wred(d);
    __syncthreads();
    if (l == 0) { shr[0][wv] = a; shr[1][wv] = bs; shr[2][wv] = d; }
    __syncthreads();
    if (tid == 0) {
      c1[w] = shr[0][0] + shr[0][1] + shr[0][2] + shr[0][3];
      c2[w] = shr[1][0] + shr[1][1] + shr[1][2] + shr[1][3];
      c3[w] = shr[2][0] + shr[2][1] + shr[2][2] + shr[2][3];
    }
  } else if (b < 336) {
    int bk = b - 320, k0 = bk * 64;
#pragma unroll
    for (int jh = 0; jh < 2; ++jh) {
      int j = tid + jh * 256;
      float g = 0.f, c = 0.f;
#pragma unroll 4
      for (int k = 0; k < 64; ++k) {
        float wv4 = w1[(size_t)(k0 + k) * DD + j];
        g = fmaf(g1[k0 + k], wv4, g);
        c = fmaf(be1[k0 + k], wv4, c);
      }
      Gp[(size_t)bk * DD + j] = g;
      Cp[(size_t)bk * DD + j] = c;
    }
  } else if (b < 400) {
    int bb = b - 336;
    f32x4 g20 = *(const f32x4*)(g2 + l * 8);
    f32x4 g21 = *(const f32x4*)(g2 + l * 8 + 4);
    f32x4 e20 = *(const f32x4*)(be2 + l * 8);
    f32x4 e21 = *(const f32x4*)(be2 + l * 8 + 4);
#pragma unroll
    for (int rr = 0; rr < 2; ++rr) {
      int k = bb * 8 + wv * 2 + rr;
      const float* row = w2 + (size_t)k * DD;
      f32x4 w0 = *(const f32x4*)(row + l * 8);
      f32x4 w1v = *(const f32x4*)(row + l * 8 + 4);
      float s1 = 0, s3 = 0, s4 = 0;
#pragma unroll
      for (int i = 0; i < 4; ++i) {
        float w = w0[i], g = g20[i];
        s1 += w; s3 = fmaf(w, g * g, s3); s4 = fmaf(w, g * e20[i], s4);
        w = w1v[i]; g = g21[i];
        s1 += w; s3 = fmaf(w, g * g, s3); s4 = fmaf(w, g * e21[i], s4);
      }
      s1 = wred(s1); s3 = wred(s3); s4 = wred(s4);
      if (l == 0) {
        V[k * 4 + 0] = s1; V[k * 4 + 1] = s3; V[k * 4 + 2] = s4; V[k * 4 + 3] = 0.f;
      }
    }
  } else {
    float a0 = 0, a1 = 0, a2 = 0;
    for (int c = tid; c < DD; c += 256) {
      float g = g2[c], be = be2[c];
      gg[c] = g * g;
      a0 = fmaf(g, g, a0); a1 = fmaf(g, be, a1); a2 = fmaf(be, be, a2);
    }
    a0 = wred(a0); a1 = wred(a1); a2 = wred(a2);
    if (l == 0) { shr[0][wv] = a0; shr[1][wv] = a1; shr[2][wv] = a2; }
    __syncthreads();
    if (tid == 0) {
      scal[0] = shr[0][0] + shr[0][1] + shr[0][2] + shr[0][3];
      scal[1] = shr[1][0] + shr[1][1] + shr[1][2] + shr[1][3];
      scal[2] = shr[2][0] + shr[2][1] + shr[2][2] + shr[2][3];
    }
  }
}

// ---------------- k_pack1: PW1T + PW1B + PCT (bf16 GEMM operands) -------------
__global__ __launch_bounds__(512) void k_pack1(
    const float* __restrict__ w1, const float* __restrict__ ln1w,
    const float* __restrict__ cmhg,
    unsigned short* __restrict__ PW1T, unsigned short* __restrict__ PW1B,
    unsigned short* __restrict__ PCT) {
  int b = blockIdx.x;
  if (b < 128) {
    int roff = (b < 64) ? 0 : 512;
    unsigned short* out = (b < 64) ? PW1T : PW1B;
    int tid = (b & 63) * 512 + threadIdx.x;
    int l = tid & 63, t = (tid >> 6) & 15, ct = tid >> 10, g = l >> 4;
    int col = (ct << 4) + (l & 15);
    ushort8 o;
#pragma unroll
    for (int i = 0; i < 8; ++i) {
      int k = t * 32 + g * 8 + i;
      o[i] = f2bf(w1[(size_t)(roff + k) * DD + col] * ln1w[roff + k]);
    }
    *(ushort8*)(out + (size_t)tid * 8) = o;
  } else {
    int tid = (b - 128) * 512 + threadIdx.x;
    int l = tid & 63, t = (tid >> 6) & 15, g = l >> 4;
    int col = ((tid >> 10) << 4) + (l & 15);
    ushort8 o;
#pragma unroll
    for (int i = 0; i < 8; ++i) {
      int k = t * 32 + g * 8 + i;
      o[i] = f2bf(cmhg[(size_t)col * DD + k]);
    }
    *(ushort8*)(PCT + (size_t)tid * 8) = o;
  }
}

// ---------------- k_gemms: 4 bf16 GEMM jobs in one dispatch -------------------
__global__ __launch_bounds__(256) void k_gemms(
    const float* __restrict__ q, const float* __restrict__ cm,
    const float* __restrict__ w2,
    const unsigned short* __restrict__ PW1T, const unsigned short* __restrict__ PW1B,
    const unsigned short* __restrict__ PCT,
    float* __restrict__ A, unsigned short* __restrict__ Bwb,
    float* __restrict__ QC, float* __restrict__ M6) {
  int b = blockIdx.x;
  const float* X; const unsigned short* PW; void* Out;
  int bx, by, ostride, obf;
  if (b < 256)      { X = q;  PW = PW1T; Out = A;    bx = b & 7;   by = b >> 3;  ostride = DD;  obf = 0; }
  else if (b < 264) { X = cm; PW = PW1B; Out = Bwb;  bx = b - 256; by = 0;       ostride = DD;  obf = 1; }
  else if (b < 296) { X = q;  PW = PCT;  Out = QC;   bx = 0;       by = b - 264; ostride = NWC; obf = 0; }
  else              { X = w2; PW = PCT;  Out = M6;   bx = 0;       by = b - 296; ostride = NWC; obf = 0; }

  int l = threadIdx.x & 63;
  int wv = threadIdx.x >> 6;
  int lr = l & 15, g = l >> 4;
  int r0 = by * 64 + wv * 16;
  int cb0 = bx * 4;
  f32x4 acc[4] = {{0,0,0,0},{0,0,0,0},{0,0,0,0},{0,0,0,0}};
  const float* xrow = X + (size_t)(r0 + lr) * DD;
#pragma unroll
  for (int t = 0; t < 16; ++t) {
    int kb = t * 32 + g * 8;
    f32x4 x0 = *(const f32x4*)(xrow + kb);
    f32x4 x1 = *(const f32x4*)(xrow + kb + 4);
    union { short8 s; unsigned u[4]; } af;
    af.u[0] = cvtpk2(x0[0], x0[1]);
    af.u[1] = cvtpk2(x0[2], x0[3]);
    af.u[2] = cvtpk2(x1[0], x1[1]);
    af.u[3] = cvtpk2(x1[2], x1[3]);
#pragma unroll
    for (int c = 0; c < 4; ++c) {
      short8 bf = *(const short8*)(PW + (size_t)(((cb0 + c) * 16 + t) * 64 + l) * 8);
      acc[c] = __builtin_amdgcn_mfma_f32_16x16x32_bf16(af.s, bf, acc[c], 0, 0, 0);
    }
  }
#pragma unroll
  for (int c = 0; c < 4; ++c)
#pragma unroll
    for (int r = 0; r < 4; ++r) {
      size_t idx = (size_t)(r0 + g * 4 + r) * ostride + (cb0 + c) * 16 + lr;
      float v = acc[c][r];
      if (obf) ((unsigned short*)Out)[idx] = f2bf(v);
      else     ((float*)Out)[idx] = v;
    }
}

// ---------------- k_pack2: i8-quantized W2X + per-col scales + PBw + G/C ------
// blocks 0..37: one 16-col tile each -> col-max, scale, quantize to PW2X (i8)
// blocks 38..41: PBw repack for K=64 fragment layout (bf16)
// block 42: G/C reduce
__global__ __launch_bounds__(512) void k_pack2(
    const float* __restrict__ w2, const float* __restrict__ M6,
    const float* __restrict__ V, const unsigned short* __restrict__ Bwb,
    const float* __restrict__ Gp, const float* __restrict__ Cp,
    const float* __restrict__ b1,
    signed char* __restrict__ PW2X, unsigned short* __restrict__ PBw,
    float* __restrict__ G, float* __restrict__ C, float* __restrict__ Scales) {
  int b = blockIdx.x, tx = threadIdx.x;
  __shared__ float red[16][33];
  __shared__ float sinv[16];
  if (b < 38) {
    int ct = b;
    int t8 = tx >> 6, l = tx & 63, g4 = l >> 4, lc = l & 15;
    int col = ct * 16 + lc;
    float v[16]; float lmax = 0.f;
#pragma unroll
    for (int i = 0; i < 16; ++i) {
      int k = t8 * 64 + g4 * 16 + i;
      float x;
      if (col < 512)      x = w2[(size_t)k * DD + col];
      else if (col < 576) x = M6[(size_t)k * 64 + (col - 512)];
      else { int cv = col - 576; x = (cv < 3) ? V[k * 4 + cv] : 0.f; }
      v[i] = x; lmax = fmaxf(lmax, fabsf(x));
    }
    red[lc][t8 * 4 + g4] = lmax;
    __syncthreads();
    if (tx < 16) {
      float m = 0.f;
#pragma unroll
      for (int j = 0; j < 32; ++j) m = fmaxf(m, red[tx][j]);
      float sc = fmaxf(m, 1e-20f) * (1.0f / 127.0f);
      Scales[ct * 16 + tx] = sc;
      sinv[tx] = 1.0f / sc;
    }
    __syncthreads();
    float inv = sinv[lc];
    u32x4 d;
#pragma unroll
    for (int j = 0; j < 4; ++j) {
      unsigned u = 0;
#pragma unroll
      for (int e = 0; e < 4; ++e) {
        float qv = v[j * 4 + e] * inv;
        qv = fminf(fmaxf(qv, -127.f), 127.f);
        int iq = (int)rintf(qv);
        u |= ((unsigned)(iq & 255)) << (8 * e);
      }
      d[j] = u;
    }
    *(u32x4*)(PW2X + (size_t)ct * 8192 + (size_t)(t8 * 64 + l) * 16) = d;
  } else if (b < 42) {
    int slot = (b - 38) * 512 + tx;  // 2048 slots
    int wt = slot >> 9, r = slot & 511, t8 = r >> 6, l = r & 63;
    int w = wt * 16 + (l & 15);
    int kb = t8 * 64 + (l >> 4) * 16;
    ushort8 o0, o1;
#pragma unroll
    for (int i = 0; i < 8; ++i) {
      o0[i] = Bwb[(size_t)w * DD + kb + i];
      o1[i] = Bwb[(size_t)w * DD + kb + 8 + i];
    }
    *(ushort8*)(PBw + (size_t)slot * 16) = o0;
    *(ushort8*)(PBw + (size_t)slot * 16 + 8) = o1;
  } else {
    int c = tx;
    float g = 0.f, cc2 = 0.f;
#pragma unroll
    for (int p = 0; p < 16; ++p) { g += Gp[p * DD + c]; cc2 += Cp[p * DD + c]; }
    G[c] = g; C[c] = cc2 + b1[c];
  }
}

// ---------------- fused main kernel: i8 GEMM, counted-vmcnt 3-ring ------------

__device__ __forceinline__ void async16(const void* g, void* lds) {
  __builtin_amdgcn_global_load_lds(
      (const __attribute__((address_space(1))) void*)(uintptr_t)g,
      (__attribute__((address_space(3))) void*)(unsigned int)(uintptr_t)lds,
      16, 0, 0);
}

__global__ __launch_bounds__(512, 2) void k_main(
    const float* __restrict__ Afull, const unsigned short* __restrict__ PBw,
    const float* __restrict__ G, const float* __restrict__ Cc,
    const float* __restrict__ q, const float* __restrict__ b2,
    const float* __restrict__ gg, const float* __restrict__ qst,
    const float* __restrict__ QC, const float* __restrict__ c1v,
    const float* __restrict__ c2v, const float* __restrict__ c3v,
    const float* __restrict__ Sq, const float* __restrict__ SSq,
    const float* __restrict__ Sc, const float* __restrict__ SSc,
    const float* __restrict__ scal, const signed char* __restrict__ PW2X,
    const float* __restrict__ Scales, float* __restrict__ out) {

  __shared__ __align__(16) float sG[DD], sC[DD], sGG[DD], sSC[608];
  __shared__ __align__(16) float sA[4][DD], sQB[4][DD];
  __shared__ __align__(16) signed char sW[3 * 16384];   // 3x16KB i8 chunk ring

  const int tid = threadIdx.x;
  const int wv = tid >> 6, l = tid & 63;
  const int g = l >> 4, lr = l & 15;
  const int n0 = blockIdx.x * 4;
  const int sub = wv >> 1;             // which n of the 4
  const int n = n0 + sub;
  const int whalf = wv & 1;
  const int w0 = whalf * 32 + lr;
  const int w1p = w0 + 16;

  // ---- stage block-wide LDS state ----
  sG[tid] = G[tid]; sC[tid] = Cc[tid]; sGG[tid] = gg[tid];
  for (int i = tid; i < 608; i += 512) sSC[i] = Scales[i] * SA_CONST;
#pragma unroll
  for (int s = 0; s < 4; ++s) {
    sA[s][tid]  = Afull[(size_t)(n0 + s) * DD + tid];
    sQB[s][tid] = q[(size_t)(n0 + s) * DD + tid] + b2[tid];
  }
  __syncthreads();

  // prefetch chunks 0,1 (hidden under the gelu phase). 2 loads/thread/chunk.
#pragma unroll
  for (int c = 0; c < 2; ++c)
#pragma unroll
    for (int j = 0; j < 2; ++j)
      async16(PW2X + (size_t)c * 16384 + (size_t)(j * 512 + tid) * 16,
              &sW[c * 16384 + (j * 512 + wv * 64) * 16]);

  // ---- LN1 scalars for this lane's two (n,w) pairs ----
  float sqn = Sq[n], ssqn = SSq[n];
  float mu0 = (sqn + Sc[w0]) * (1.0f / 1024.0f);
  float rs0 = rsqrtf((ssqn + SSc[w0]) * (1.0f / 1024.0f) - mu0 * mu0 + 1e-5f);
  float mu1 = (sqn + Sc[w1p]) * (1.0f / 1024.0f);
  float rs1 = rsqrtf((ssqn + SSc[w1p]) * (1.0f / 1024.0f) - mu1 * mu1 + 1e-5f);
  float al0 = rs0, bl0 = -rs0 * mu0;
  float al1 = rs1, bl1 = -rs1 * mu1;

  // ---- gelu fragments -> i8 MFMA B-operand layout (k = t8*64 + g*16 + i) ----
  i32v4 af0[8], af1[8];
  const unsigned short* pb0 = PBw + (size_t)(whalf * 2) * 8192;
  const unsigned short* pb1 = PBw + (size_t)(whalf * 2 + 1) * 8192;
#pragma unroll
  for (int t8 = 0; t8 < 8; ++t8) {
    int kb = t8 * 64 + g * 16;
    ushort8 u0a = *(const ushort8*)(pb0 + (size_t)(t8 * 64 + l) * 16);
    ushort8 u0b = *(const ushort8*)(pb0 + (size_t)(t8 * 64 + l) * 16 + 8);
    ushort8 u1a = *(const ushort8*)(pb1 + (size_t)(t8 * 64 + l) * 16);
    ushort8 u1b = *(const ushort8*)(pb1 + (size_t)(t8 * 64 + l) * 16 + 8);
    unsigned dw0[4], dw1[4];
#pragma unroll
    for (int j = 0; j < 4; ++j) {
      f32x4 av = *(const f32x4*)&sA[sub][kb + j * 4];
      f32x4 gv = *(const f32x4*)&sG[kb + j * 4];
      f32x4 cv = *(const f32x4*)&sC[kb + j * 4];
      float hA[4], hB[4];
#pragma unroll
      for (int i2 = 0; i2 < 4; ++i2) {
        int e = j * 4 + i2;
        float bw0 = bf2f(e < 8 ? u0a[e & 7] : u0b[e & 7]);
        float bw1 = bf2f(e < 8 ? u1a[e & 7] : u1b[e & 7]);
        float base0 = fmaf(bl0, gv[i2], cv[i2]);
        float base1 = fmaf(bl1, gv[i2], cv[i2]);
        hA[i2] = gelu31(fmaf(al0, av[i2] + bw0, base0));
        hB[i2] = gelu31(fmaf(al1, av[i2] + bw1, base1));
      }
      dw0[j] = pk4i8(hA[0], hA[1], hA[2], hA[3]);
      dw1[j] = pk4i8(hB[0], hB[1], hB[2], hB[3]);
    }
    i32v4 a0v = {(int)dw0[0], (int)dw0[1], (int)dw0[2], (int)dw0[3]};
    i32v4 a1v = {(int)dw1[0], (int)dw1[1], (int)dw1[2], (int)dw1[3]};
    af0[t8] = a0v; af1[t8] = a1v;
  }

  float S20 = 0.f, S50 = 0.f, S21 = 0.f, S51 = 0.f;
  int m6i0 = 0, m6i1 = 0;
  int v1i0 = 0, v3i0 = 0, v4i0 = 0;
  int v1i1 = 0, v3i1 = 0, v4i1 = 0;

  for (int cc = 0; cc < NCHUNK; ++cc) {
    // counted waits: chunk cc landed; cc+1's 2 loads stay in flight.
    if (cc < NCHUNK - 1) asm volatile("s_waitcnt vmcnt(2)" ::: "memory");
    else                 asm volatile("s_waitcnt vmcnt(0)" ::: "memory");
    asm volatile("s_waitcnt lgkmcnt(0)" ::: "memory");
    __builtin_amdgcn_s_barrier();
    if (cc + 2 < NCHUNK) {             // prefetch depth 2 into ring slot
      const signed char* src = PW2X + (size_t)(cc + 2) * 16384;
      signed char* dst = &sW[((cc + 2) % 3) * 16384];
#pragma unroll
      for (int j = 0; j < 2; ++j)
        async16(src + (size_t)(j * 512 + tid) * 16, dst + (j * 512 + wv * 64) * 16);
    }
    const signed char* wbuf = &sW[(cc % 3) * 16384];

    if (cc < 16) {
      i32v4 acc00 = {0,0,0,0}, acc01 = {0,0,0,0}, acc10 = {0,0,0,0}, acc11 = {0,0,0,0};
      __builtin_amdgcn_s_setprio(1);
#pragma unroll
      for (int t8 = 0; t8 < 8; ++t8) {
        i32v4 bf0 = *(const i32v4*)(wbuf + (size_t)(t8 * 64 + l) * 16);
        i32v4 bf1 = *(const i32v4*)(wbuf + 8192 + (size_t)(t8 * 64 + l) * 16);
        acc00 = __builtin_amdgcn_mfma_i32_16x16x64_i8(bf0, af0[t8], acc00, 0, 0, 0);
        acc10 = __builtin_amdgcn_mfma_i32_16x16x64_i8(bf0, af1[t8], acc10, 0, 0, 0);
        acc01 = __builtin_amdgcn_mfma_i32_16x16x64_i8(bf1, af0[t8], acc01, 0, 0, 0);
        acc11 = __builtin_amdgcn_mfma_i32_16x16x64_i8(bf1, af1[t8], acc11, 0, 0, 0);
      }
      __builtin_amdgcn_s_setprio(0);
#pragma unroll
      for (int ct = 0; ct < 2; ++ct) {
        int cb = cc * 32 + ct * 16 + g * 4;
        f32x4 qb4 = *(const f32x4*)&sQB[sub][cb];
        f32x4 gg4 = *(const f32x4*)&sGG[cb];
        f32x4 sc4 = *(const f32x4*)&sSC[cb];
        i32v4 aAv = ct ? acc01 : acc00;
        i32v4 aBv = ct ? acc11 : acc10;
#pragma unroll
        for (int r = 0; r < 4; ++r) {
          float y = fmaf((float)aAv[r], sc4[r], qb4[r]);
          float y2 = y * y;
          S20 += y2; S50 = fmaf(y2, gg4[r], S50);
          float z = fmaf((float)aBv[r], sc4[r], qb4[r]);
          float z2 = z * z;
          S21 += z2; S51 = fmaf(z2, gg4[r], S51);
        }
      }
    } else if (cc == 16 + whalf) {
      i32v4 acc00 = {0,0,0,0}, acc11 = {0,0,0,0};
      __builtin_amdgcn_s_setprio(1);
#pragma unroll
      for (int t8 = 0; t8 < 8; ++t8) {
        i32v4 bf0 = *(const i32v4*)(wbuf + (size_t)(t8 * 64 + l) * 16);
        i32v4 bf1 = *(const i32v4*)(wbuf + 8192 + (size_t)(t8 * 64 + l) * 16);
        acc00 = __builtin_amdgcn_mfma_i32_16x16x64_i8(bf0, af0[t8], acc00, 0, 0, 0);
        acc11 = __builtin_amdgcn_mfma_i32_16x16x64_i8(bf1, af1[t8], acc11, 0, 0, 0);
      }
      __builtin_amdgcn_s_setprio(0);
      int d0 = sel4i(acc00, lr & 3);
      int d1 = sel4i(acc11, lr & 3);
      int src = lr + ((lr >> 2) << 4);
      m6i0 = __shfl(d0, src, 64);
      m6i1 = __shfl(d1, src, 64);
    } else if (cc == 18) {
      i32v4 acc00 = {0,0,0,0}, acc10 = {0,0,0,0};
      __builtin_amdgcn_s_setprio(1);
#pragma unroll
      for (int t8 = 0; t8 < 8; ++t8) {
        i32v4 bf0 = *(const i32v4*)(wbuf + (size_t)(t8 * 64 + l) * 16);
        acc00 = __builtin_amdgcn_mfma_i32_16x16x64_i8(bf0, af0[t8], acc00, 0, 0, 0);
        acc10 = __builtin_amdgcn_mfma_i32_16x16x64_i8(bf0, af1[t8], acc10, 0, 0, 0);
      }
      __builtin_amdgcn_s_setprio(0);
      v1i0 = __shfl(acc00[0], lr, 64);
      v3i0 = __shfl(acc00[1], lr, 64);
      v4i0 = __shfl(acc00[2], lr, 64);
      v1i1 = __shfl(acc10[0], lr, 64);
      v3i1 = __shfl(acc10[1], lr, 64);
      v4i1 = __shfl(acc10[2], lr, 64);
    }
  }

  S20 += __shfl_xor(S20, 16, 64); S20 += __shfl_xor(S20, 32, 64);
  S50 += __shfl_xor(S50, 16, 64); S50 += __shfl_xor(S50, 32, 64);
  S21 += __shfl_xor(S21, 16, 64); S21 += __shfl_xor(S21, 32, 64);
  S51 += __shfl_xor(S51, 16, 64); S51 += __shfl_xor(S51, 32, 64);

  if (g == 0) {
    float sg2v = scal[0], sgbv = scal[1], sb2v = scal[2];
    float qbs = qst[n * 4 + 0], qggs = qst[n * 4 + 1], qgbs = qst[n * 4 + 2];
#pragma unroll
    for (int p = 0; p < 2; ++p) {
      int w = whalf * 32 + p * 16 + lr;
      float v1f = (float)(p ? v1i1 : v1i0) * sSC[576];
      float v3f = (float)(p ? v3i1 : v3i0) * sSC[577];
      float v4f = (float)(p ? v4i1 : v4i0) * sSC[578];
      float m6f = (float)(p ? m6i1 : m6i0) * sSC[512 + w];
      float S1 = v1f + qbs;
      float S2 = (p ? S21 : S20);
      float S3 = v3f + qggs;
      float S4 = v4f + qgbs;
      float S5 = (p ? S51 : S50);
      float S6 = m6f + QC[(size_t)n * NWC + w] + c3v[w];
      float mu2 = S1 * (1.0f / 512.0f);
      float var2 = S2 * (1.0f / 512.0f) - mu2 * mu2;
      float rs2 = rsqrtf(var2 + 1e-5f);
      float n2 = rs2 * rs2 * (S5 - 2.f * mu2 * S3 + mu2 * mu2 * sg2v)
               + 2.f * rs2 * (S4 - mu2 * sgbv) + sb2v;
      float num = rs2 * (S6 - mu2 * c1v[w]) + c2v[w];
      out[(size_t)n * NWC + w] = 16.0f * num / fmaxf(sqrtf(fmaxf(n2, 0.f)), 1e-12f);
    }
  }
}

// ---------------- launch ----------------

extern "C" void kernel_launch(void* const* d_in, const int* in_sizes, int n_in,
                              void* d_out, int out_size, void* d_ws, size_t ws_size,
                              hipStream_t stream) {
  const float* q    = (const float*)d_in[0];
  const float* cm   = (const float*)d_in[1];
  const float* ln1w = (const float*)d_in[2];
  const float* ln1b = (const float*)d_in[3];
  const float* w1   = (const float*)d_in[4];
  const float* b1   = (const float*)d_in[5];
  const float* w2   = (const float*)d_in[6];
  const float* b2   = (const float*)d_in[7];
  const float* ln2w = (const float*)d_in[8];
  const float* ln2b = (const float*)d_in[9];
  float* out = (float*)d_out;

  char* p = (char*)d_ws;
  auto alloc = [&](size_t bytes) { char* r = p; p += (bytes + 255) & ~(size_t)255; return r; };
  float* A     = (float*)alloc((size_t)NQ * DD * 4);
  unsigned short* Bwb = (unsigned short*)alloc((size_t)NWC * DD * 2);
  float* G     = (float*)alloc(DD * 4);
  float* C     = (float*)alloc(DD * 4);
  float* Gp    = (float*)alloc((size_t)16 * DD * 4);
  float* Cp    = (float*)alloc((size_t)16 * DD * 4);
  float* Sq    = (float*)alloc(NQ * 4);
  float* SSq   = (float*)alloc(NQ * 4);
  float* Sc    = (float*)alloc(NWC * 4);
  float* SSc   = (float*)alloc(NWC * 4);
  float* cmhg  = (float*)alloc((size_t)NWC * DD * 4);
  float* c1    = (float*)alloc(NWC * 4);
  float* c2    = (float*)alloc(NWC * 4);
  float* c3    = (float*)alloc(NWC * 4);
  float* gg    = (float*)alloc(DD * 4);
  float* scal  = (float*)alloc(256);
  float* qst   = (float*)alloc((size_t)NQ * 4 * 4);
  float* QC    = (float*)alloc((size_t)NQ * NWC * 4);
  float* M6buf = (float*)alloc((size_t)DD * NWC * 4);
  float* Vbuf  = (float*)alloc((size_t)DD * 4 * 4);
  float* Scl   = (float*)alloc(608 * 4);
  unsigned short* PW1T = (unsigned short*)alloc((size_t)DD * DD * 2);
  unsigned short* PW1B = (unsigned short*)alloc((size_t)DD * DD * 2);
  unsigned short* PCT  = (unsigned short*)alloc((size_t)DD * NWC * 2);
  unsigned short* PBw  = (unsigned short*)alloc((size_t)NWC * DD * 2);
  signed char* PW2X    = (signed char*)alloc((size_t)38 * 8192);

  k_prep<<<401, 256, 0, stream>>>(q, cm, ln1w, ln1b, w1, w2, ln2w, ln2b, b2,
                                  Sq, SSq, qst, Sc, SSc, cmhg, c1, c2, c3,
                                  Gp, Cp, Vbuf, gg, scal);
  k_pack1<<<136, 512, 0, stream>>>(w1, ln1w, cmhg, PW1T, PW1B, PCT);
  k_gemms<<<304, 256, 0, stream>>>(q, cm, w2, PW1T, PW1B, PCT, A, Bwb, QC, M6buf);
  k_pack2<<<43, 512, 0, stream>>>(w2, M6buf, Vbuf, Bwb, Gp, Cp, b1, PW2X, PBw, G, C, Scl);
  k_main<<<512, 512, 0, stream>>>(A, PBw, G, C, q, b2, gg, qst, QC, c1, c2, c3,
                                  Sq, SSq, Sc, SSc, scal, PW2X, Scl, out);
}